// Round 12
// baseline (3016.461 us; speedup 1.0000x reference)
//
#include <hip/hip_runtime.h>
#include <cstddef>
#include <cstdint>

#define EPS_BN 1e-5f
#define NBINS 4
#define NEG_INF (-__builtin_inff())

// =====================================================================
// Tiled fp32 GEMM:  Y[r][o] = sum_ci X'[r][ci] * W[o][ci]   (Y = X' W^T)
// 128x128 tile, BK=16, 256 threads, 8x8 microtile/thread (split
// quadrants, <=2-way LDS reads). R multiple of 128; Cout guarded.
// FUSE_IN: X' = relu((X - mean)*scale) from st_in bins (prev layer BN).
// Epilogue: per-column sum/sumsq accumulated into st_out bins.
// =====================================================================
template <bool FUSE_IN>
__global__ __launch_bounds__(256) void gemm_xwt(const float* __restrict__ X,
                                                const float* __restrict__ Wm,
                                                float* __restrict__ Y,
                                                int R, int Cin, int Cout,
                                                const float* __restrict__ st_in, int Rin,
                                                float* __restrict__ st_out) {
  __shared__ __align__(16) float Xs[16][132];
  __shared__ __align__(16) float Ws[16][132];
  __shared__ float sMean[512], sScale[512];
  const int t  = threadIdx.x;
  const int r0 = blockIdx.x << 7;
  const int n0 = blockIdx.y << 7;
  const int tx = t & 15;
  const int ty = t >> 4;

  if constexpr (FUSE_IN) {
    const float inv = 1.f / (float)Rin;
    for (int k = t; k < Cin; k += 256) {
      float s = 0.f, q = 0.f;
#pragma unroll
      for (int bn = 0; bn < NBINS; ++bn) {
        s += st_in[bn * 2 * Cin + k];
        q += st_in[bn * 2 * Cin + Cin + k];
      }
      const float m  = s * inv;
      const float vr = fmaf(-m, m, q * inv);
      sMean[k]  = m;
      sScale[k] = rsqrtf(vr + EPS_BN);
    }
    __syncthreads();
  }

  float acc[8][8] = {};
  const int rStage = t >> 1;
  const int kBase  = (t & 1) << 3;
  const int nr     = n0 + rStage;

  for (int k0 = 0; k0 < Cin; k0 += 16) {
    const float* xrow = X  + (size_t)(r0 + rStage) * Cin + k0 + kBase;
    const float* wrow = Wm + (size_t)nr * Cin + k0 + kBase;
    if (((Cin & 3) == 0) && (k0 + 16 <= Cin)) {
      float4 xa = *(const float4*)(xrow);
      float4 xb = *(const float4*)(xrow + 4);
      if constexpr (FUSE_IN) {
        const int kb = k0 + kBase;
        xa.x = fmaxf(0.f, (xa.x - sMean[kb + 0]) * sScale[kb + 0]);
        xa.y = fmaxf(0.f, (xa.y - sMean[kb + 1]) * sScale[kb + 1]);
        xa.z = fmaxf(0.f, (xa.z - sMean[kb + 2]) * sScale[kb + 2]);
        xa.w = fmaxf(0.f, (xa.w - sMean[kb + 3]) * sScale[kb + 3]);
        xb.x = fmaxf(0.f, (xb.x - sMean[kb + 4]) * sScale[kb + 4]);
        xb.y = fmaxf(0.f, (xb.y - sMean[kb + 5]) * sScale[kb + 5]);
        xb.z = fmaxf(0.f, (xb.z - sMean[kb + 6]) * sScale[kb + 6]);
        xb.w = fmaxf(0.f, (xb.w - sMean[kb + 7]) * sScale[kb + 7]);
      }
      Xs[kBase + 0][rStage] = xa.x; Xs[kBase + 1][rStage] = xa.y;
      Xs[kBase + 2][rStage] = xa.z; Xs[kBase + 3][rStage] = xa.w;
      Xs[kBase + 4][rStage] = xb.x; Xs[kBase + 5][rStage] = xb.y;
      Xs[kBase + 6][rStage] = xb.z; Xs[kBase + 7][rStage] = xb.w;
      float4 wa = {0, 0, 0, 0}, wb = {0, 0, 0, 0};
      if (nr < Cout) { wa = *(const float4*)(wrow); wb = *(const float4*)(wrow + 4); }
      Ws[kBase + 0][rStage] = wa.x; Ws[kBase + 1][rStage] = wa.y;
      Ws[kBase + 2][rStage] = wa.z; Ws[kBase + 3][rStage] = wa.w;
      Ws[kBase + 4][rStage] = wb.x; Ws[kBase + 5][rStage] = wb.y;
      Ws[kBase + 6][rStage] = wb.z; Ws[kBase + 7][rStage] = wb.w;
    } else {
#pragma unroll
      for (int u = 0; u < 8; ++u) {
        const int k = k0 + kBase + u;
        float xe = 0.f, we = 0.f;
        if (k < Cin) {
          xe = xrow[u];
          if constexpr (FUSE_IN) xe = fmaxf(0.f, (xe - sMean[k]) * sScale[k]);
          if (nr < Cout) we = wrow[u];
        }
        Xs[kBase + u][rStage] = xe;
        Ws[kBase + u][rStage] = we;
      }
    }
    __syncthreads();
#pragma unroll
    for (int kk = 0; kk < 16; ++kk) {
      const float4 a0 = *(const float4*)(&Xs[kk][ty << 2]);
      const float4 a1 = *(const float4*)(&Xs[kk][64 + (ty << 2)]);
      const float4 b0 = *(const float4*)(&Ws[kk][tx << 2]);
      const float4 b1 = *(const float4*)(&Ws[kk][64 + (tx << 2)]);
      const float av[8] = {a0.x, a0.y, a0.z, a0.w, a1.x, a1.y, a1.z, a1.w};
      const float bw[8] = {b0.x, b0.y, b0.z, b0.w, b1.x, b1.y, b1.z, b1.w};
#pragma unroll
      for (int i = 0; i < 8; ++i)
#pragma unroll
        for (int j = 0; j < 8; ++j) acc[i][j] = fmaf(av[i], bw[j], acc[i][j]);
    }
    __syncthreads();
  }
#pragma unroll
  for (int h = 0; h < 2; ++h)
#pragma unroll
    for (int i = 0; i < 4; ++i) {
      const int r = r0 + h * 64 + (ty << 2) + i;
      float* yr = Y + (size_t)r * Cout;
#pragma unroll
      for (int g = 0; g < 2; ++g) {
        const int n = n0 + g * 64 + (tx << 2);
        if (n < Cout) {
          float4 o = {acc[h * 4 + i][g * 4 + 0], acc[h * 4 + i][g * 4 + 1],
                      acc[h * 4 + i][g * 4 + 2], acc[h * 4 + i][g * 4 + 3]};
          *(float4*)(yr + n) = o;
        }
      }
    }
#pragma unroll
  for (int g = 0; g < 2; ++g)
#pragma unroll
    for (int j = 0; j < 4; ++j) {
      float s = 0.f, q = 0.f;
#pragma unroll
      for (int rh = 0; rh < 8; ++rh) {
        const float v = acc[rh][g * 4 + j];
        s += v;
        q = fmaf(v, v, q);
      }
      Xs[ty][g * 64 + (tx << 2) + j] = s;
      Ws[ty][g * 64 + (tx << 2) + j] = q;
    }
  __syncthreads();
  if (t < 128) {
    const int n = n0 + t;
    if (n < Cout) {
      float s = 0.f, q = 0.f;
#pragma unroll
      for (int w = 0; w < 16; ++w) { s += Xs[w][t]; q += Ws[w][t]; }
      float* dst = st_out + (blockIdx.x & (NBINS - 1)) * 2 * Cout;
      atomicAdd(dst + n, s);
      atomicAdd(dst + Cout + n, q);
    }
  }
}

// normalize -> relu -> max over ns rows per group
__global__ void bn_apply_relu_maxpool(const float* __restrict__ Y,
                                      const float* __restrict__ st,
                                      float* __restrict__ o, int G, int ns, int C) {
  const int i = blockIdx.x * 256 + threadIdx.x;
  if (i >= G * C) return;
  const int c = i % C;
  const int g = i / C;
  float s = 0.f, q = 0.f;
#pragma unroll
  for (int bn = 0; bn < NBINS; ++bn) {
    s += st[bn * 2 * C + c];
    q += st[bn * 2 * C + C + c];
  }
  const int R = G * ns;
  const float inv = 1.f / (float)R;
  const float m  = s * inv;
  const float vr = fmaf(-m, m, q * inv);
  const float sc = rsqrtf(vr + EPS_BN);
  const float* p = Y + (size_t)g * ns * C + c;
  float mx = NEG_INF;
  for (int k = 0; k < ns; ++k) mx = fmaxf(mx, p[(size_t)k * C]);
  o[i] = fmaxf(0.f, (mx - m) * sc);
}

// =====================================================================
// FPS spatial sort (per batch): Morton 16^3 cells, counting sort into
// float4 {x,y,z,bitcast(orig_idx)}; pads to 20480 with first point's
// coords + huge idx. Pure permutation; FPS results are permutation-
// invariant (validated end-to-end in R9: passed + replay-stable).
// =====================================================================
__device__ inline int fps_cell(float x, float y, float z) {
  int cx = (int)(x * 16.f); cx = cx < 0 ? 0 : (cx > 15 ? 15 : cx);
  int cy = (int)(y * 16.f); cy = cy < 0 ? 0 : (cy > 15 ? 15 : cy);
  int cz = (int)(z * 16.f); cz = cz < 0 ? 0 : (cz > 15 ? 15 : cz);
  auto sp = [](int v) { return (v & 1) | ((v & 2) << 2) | ((v & 4) << 4) | ((v & 8) << 6); };
  return sp(cx) | (sp(cy) << 1) | (sp(cz) << 2);
}

__global__ __launch_bounds__(1024)
void fps_sort_kernel(const float* __restrict__ xyz, float4* __restrict__ sorted) {
  const int b = blockIdx.x, tid = threadIdx.x;
  const float* p = xyz + (size_t)b * 20000 * 3;
  __shared__ int hist[4096];
  __shared__ int base[4096];
  __shared__ int wsum[64];
  for (int i = tid; i < 4096; i += 1024) hist[i] = 0;
  __syncthreads();
#pragma unroll
  for (int k = 0; k < 20; ++k) {
    const int i = tid + k * 1024;
    if (i < 20000) atomicAdd(&hist[fps_cell(p[i * 3], p[i * 3 + 1], p[i * 3 + 2])], 1);
  }
  __syncthreads();
  if (tid < 64) {
    int s = 0;
    for (int j = 0; j < 64; ++j) s += hist[tid * 64 + j];
    wsum[tid] = s;
  }
  __syncthreads();
  if (tid == 0) {
    int r = 0;
    for (int j = 0; j < 64; ++j) { const int v = wsum[j]; wsum[j] = r; r += v; }
  }
  __syncthreads();
  if (tid < 64) {
    int r = wsum[tid];
    for (int j = 0; j < 64; ++j) { const int c = tid * 64 + j; const int h = hist[c]; base[c] = r; r += h; }
  }
  __syncthreads();
  float4* sb = sorted + (size_t)b * 20480;
#pragma unroll
  for (int k = 0; k < 20; ++k) {
    const int i = tid + k * 1024;
    if (i < 20000) {
      const float x = p[i * 3], y = p[i * 3 + 1], z = p[i * 3 + 2];
      const int pos = atomicAdd(&base[fps_cell(x, y, z)], 1);
      float4 q; q.x = x; q.y = y; q.z = z; q.w = __int_as_float(i);
      sb[pos] = q;
    }
  }
  const float x0 = p[0], y0 = p[1], z0 = p[2];
  for (int i = 20000 + tid; i < 20480; i += 1024) {
    float4 q; q.x = x0; q.y = y0; q.z = z0; q.w = __int_as_float(0x3fffffff);
    sb[i] = q;
  }
}

// =====================================================================
// FPS SA1 (20000 -> 512) v6 = R5's reduce skeleton + R9's prune math.
// 1024 threads / 16 waves (R5-validated latency hiding). Thread owns 20
// contiguous Morton-sorted points (tight AABB); dd in 80KB LDS
// [slot][tid] (2-way, free); carried (cbv,cbi,cbx,cby,cbz)+AABB in regs
// (~40 live, no spill). Per step: one exact AABB lower-bound test
// (monotone rn op tree; skip => every min-update provably a no-op,
// validated R6-R9); rescan streams the 20 float4s from L2 (16 waves
// hide latency — R7's failure was 1 wave/SIMD). Reduce path is R5
// VERBATIM (2-value butterfly, unique-orig-index owner-detect, coords
// published through sv/sx/sy/sz -> bc, two barriers): no global access
// and no wide butterfly in the serial chain (R6/R9 failure causes).
// Tie-breaks are smallest ORIGINAL index everywhere (R9-validated;
// sorted scan order != index order, so the explicit == compare is
// required, unlike R5's ascending-order scan).
// =====================================================================
__global__ __launch_bounds__(1024)
void fps_sa1_kernel(const float* __restrict__ xyz, const float4* __restrict__ sorted,
                    float* __restrict__ new_xyz) {
  const int b    = blockIdx.x;
  const int tid  = threadIdx.x;
  const int lane = tid & 63;
  const int wave = tid >> 6;  // 0..15
  const float* p = xyz + (size_t)b * 20000 * 3;
  const float4* sp = sorted + (size_t)b * 20480 + tid * 20;

  __shared__ float ddL[20 * 1024];  // 80 KB, [slot][thread] -> 2-way banks
  __shared__ float sv[16], sx[16], sy[16], sz[16];
  __shared__ int   si[16];
  __shared__ float bc[3];

  float mnx = 1e30f, mny = 1e30f, mnz = 1e30f;
  float mxx = -1e30f, mxy = -1e30f, mxz = -1e30f;
  float cbv = NEG_INF, cbx = 0.f, cby = 0.f, cbz = 0.f;
  int   cbi = 0x7fffffff;

#pragma unroll
  for (int j = 0; j < 20; ++j) {
    const float4 q = sp[j];
    const int qi = __float_as_int(q.w);
    mnx = fminf(mnx, q.x); mny = fminf(mny, q.y); mnz = fminf(mnz, q.z);
    mxx = fmaxf(mxx, q.x); mxy = fmaxf(mxy, q.y); mxz = fmaxf(mxz, q.z);
    const float d0 = (qi < 20000) ? 1e10f : NEG_INF;
    ddL[j * 1024 + tid] = d0;
    if (d0 > cbv || (d0 == cbv && qi < cbi)) {
      cbv = d0; cbi = qi; cbx = q.x; cby = q.y; cbz = q.z;
    }
  }

  float fx = p[0], fy = p[1], fz = p[2];
  if (tid == 0) {
    float* o = new_xyz + (size_t)b * 512 * 3;
    o[0] = fx; o[1] = fy; o[2] = fz;
  }
  __syncthreads();

  for (int s = 1; s < 512; ++s) {
    // exact lower bound of d^2 from far point to this thread's AABB
    const float ax = fmaxf(fmaxf(mnx - fx, fx - mxx), 0.f);
    const float ay = fmaxf(fmaxf(mny - fy, fy - mxy), 0.f);
    const float az = fmaxf(fmaxf(mnz - fz, fz - mxz), 0.f);
    const float dm = __fadd_rn(__fadd_rn(__fmul_rn(ax, ax), __fmul_rn(ay, ay)),
                               __fmul_rn(az, az));
    if (dm < cbv) {  // rescan: some owned dd may shrink
      cbv = NEG_INF; cbi = 0x7fffffff;
#pragma unroll
      for (int j = 0; j < 20; ++j) {
        const float4 q = sp[j];
        const int qi = __float_as_int(q.w);
        const float dx = q.x - fx, dy = q.y - fy, dz = q.z - fz;
        const float d = __fadd_rn(__fadd_rn(__fmul_rn(dx, dx), __fmul_rn(dy, dy)),
                                  __fmul_rn(dz, dz));
        const int a = j * 1024 + tid;
        const float nd = fminf(ddL[a], d);
        ddL[a] = nd;
        if (nd > cbv || (nd == cbv && qi < cbi)) {
          cbv = nd; cbi = qi; cbx = q.x; cby = q.y; cbz = q.z;
        }
      }
    }
    // ---- R5-verbatim reduce: butterfly on (v,i), owner-detect publish ----
    float v  = cbv;
    int   i0 = cbi;
#pragma unroll
    for (int m = 1; m < 64; m <<= 1) {
      const float ov = __shfl_xor(v, m, 64);
      const int   oi = __shfl_xor(i0, m, 64);
      if (ov > v || (ov == v && oi < i0)) { v = ov; i0 = oi; }
    }
    if (i0 == cbi) {  // unique owner lane (orig indices unique per lane)
      sv[wave] = cbv; si[wave] = cbi; sx[wave] = cbx; sy[wave] = cby; sz[wave] = cbz;
    }
    __syncthreads();
    if (tid < 64) {
      const float lv = (lane < 16) ? sv[lane] : NEG_INF;
      const int   li = (lane < 16) ? si[lane] : 0x7fffffff;
      float v2 = lv;
      int   i2 = li;
#pragma unroll
      for (int m = 1; m < 16; m <<= 1) {
        const float ov = __shfl_xor(v2, m, 64);
        const int   oi = __shfl_xor(i2, m, 64);
        if (ov > v2 || (ov == v2 && oi < i2)) { v2 = ov; i2 = oi; }
      }
      if (lane < 16 && li == i2) {  // unique global owner
        const float wx = sx[lane], wy = sy[lane], wz = sz[lane];
        bc[0] = wx; bc[1] = wy; bc[2] = wz;
        float* o = new_xyz + ((size_t)b * 512 + s) * 3;
        o[0] = wx; o[1] = wy; o[2] = wz;
      }
    }
    __syncthreads();
    fx = bc[0]; fy = bc[1]; fz = bc[2];
  }
}

// =====================================================================
// FPS small (SA2: 512 -> 128), one block per batch, all state in regs.
// =====================================================================
template <int N, int NP, int THREADS, int NPT>
__global__ __launch_bounds__(THREADS)
void fps2_kernel(const float* __restrict__ xyz, float* __restrict__ new_xyz) {
  constexpr int NW = THREADS / 64;
  const int b    = blockIdx.x;
  const int tid  = threadIdx.x;
  const int lane = tid & 63;
  const int wave = tid >> 6;
  const float* p = xyz + (size_t)b * N * 3;
  float px[NPT], py[NPT], pz[NPT], dd[NPT];
#pragma unroll
  for (int j = 0; j < NPT; ++j) {
    const int i = tid + j * THREADS;
    if (i < N) {
      px[j] = p[i * 3 + 0];
      py[j] = p[i * 3 + 1];
      pz[j] = p[i * 3 + 2];
      dd[j] = 1e10f;
    } else {
      px[j] = 0.f; py[j] = 0.f; pz[j] = 0.f;
      dd[j] = NEG_INF;
    }
  }
  __shared__ float sv[NW], sx[NW], sy[NW], sz[NW];
  __shared__ int   si[NW];
  __shared__ float bc[3];
  float fx = p[0], fy = p[1], fz = p[2];
  if (tid == 0) {
    float* o = new_xyz + (size_t)b * NP * 3;
    o[0] = fx; o[1] = fy; o[2] = fz;
  }
  for (int s = 1; s < NP; ++s) {
    float bv = NEG_INF;
    int   bi = 0x7fffffff;
    float bx = 0.f, by = 0.f, bz = 0.f;
#pragma unroll
    for (int j = 0; j < NPT; ++j) {
      const float dx = px[j] - fx;
      const float dy = py[j] - fy;
      const float dz = pz[j] - fz;
      const float d  = __fadd_rn(__fadd_rn(__fmul_rn(dx, dx), __fmul_rn(dy, dy)),
                                 __fmul_rn(dz, dz));
      const float nd = fminf(dd[j], d);
      dd[j] = nd;
      if (nd > bv) { bv = nd; bi = tid + j * THREADS; bx = px[j]; by = py[j]; bz = pz[j]; }
    }
    float v = bv;
    int   i0 = bi;
#pragma unroll
    for (int m = 1; m < 64; m <<= 1) {
      const float ov = __shfl_xor(v, m, 64);
      const int   oi = __shfl_xor(i0, m, 64);
      if (ov > v || (ov == v && oi < i0)) { v = ov; i0 = oi; }
    }
    if (i0 == bi) {
      sv[wave] = bv; si[wave] = bi; sx[wave] = bx; sy[wave] = by; sz[wave] = bz;
    }
    __syncthreads();
    if (tid < 64) {
      const float lv = (lane < NW) ? sv[lane] : NEG_INF;
      const int   li = (lane < NW) ? si[lane] : 0x7fffffff;
      float v2 = lv;
      int   i2 = li;
#pragma unroll
      for (int m = 1; m < NW; m <<= 1) {
        const float ov = __shfl_xor(v2, m, 64);
        const int   oi = __shfl_xor(i2, m, 64);
        if (ov > v2 || (ov == v2 && oi < i2)) { v2 = ov; i2 = oi; }
      }
      if (lane < NW && li == i2) {
        const float wx = sx[lane], wy = sy[lane], wz = sz[lane];
        bc[0] = wx; bc[1] = wy; bc[2] = wz;
        float* o = new_xyz + ((size_t)b * NP + s) * 3;
        o[0] = wx; o[1] = wy; o[2] = wz;
      }
    }
    __syncthreads();
    fx = bc[0]; fy = bc[1]; fz = bc[2];
  }
}

// =====================================================================
// Ball query: ONE WAVE PER CENTER, ballot + prefix-popcount (R11,
// validated). Emits the first NS qualifying indices in ascending order.
// =====================================================================
template <int N, int NS>
__global__ __launch_bounds__(256)
void ballquery_wave_kernel(const float* __restrict__ centers,
                           const float* __restrict__ pts,
                           int* __restrict__ idx, int BS, int S, float r2) {
  const int w    = (blockIdx.x * 256 + threadIdx.x) >> 6;  // global wave id
  const int lane = threadIdx.x & 63;
  if (w >= BS) return;
  const int b = w / S;
  const float cx = centers[w * 3 + 0];
  const float cy = centers[w * 3 + 1];
  const float cz = centers[w * 3 + 2];
  const float* p = pts + (size_t)b * N * 3;
  int* o = idx + (size_t)w * NS;
  int total = 0;
  int first = -1;
  for (int i0 = 0; i0 < N && total < NS; i0 += 64) {
    const int i = i0 + lane;
    bool pred = false;
    if (i < N) {
      const float dx = cx - p[i * 3 + 0];
      const float dy = cy - p[i * 3 + 1];
      const float dz = cz - p[i * 3 + 2];
      const float d2 = __fadd_rn(__fadd_rn(__fmul_rn(dx, dx), __fmul_rn(dy, dy)),
                                 __fmul_rn(dz, dz));
      pred = (d2 < r2);
    }
    const unsigned long long mask = __ballot(pred);
    if (mask) {
      const unsigned long long below = (lane == 0) ? 0ull : (mask << (64 - lane));
      const int before = __popcll(below);
      if (pred && (total + before) < NS) o[total + before] = i;
      if (first < 0) first = i0 + (__ffsll((long long)mask) - 1);  // wave-uniform
      total += __popcll(mask);
    }
  }
  if (lane >= total && lane < NS) o[lane] = first;
}

// =====================================================================
// Grouping / concat kernels
// =====================================================================
__global__ void group1_kernel(const float* __restrict__ xyz, const float* __restrict__ ctr,
                              const int* __restrict__ idx, float* __restrict__ X1) {
  const int t = blockIdx.x * 256 + threadIdx.x;
  if (t >= 8 * 512 * 32) return;
  const int g = t >> 5;
  const int b = g >> 9;
  const int i = idx[t];
  const float* p = xyz + ((size_t)b * 20000 + i) * 3;
  const float* c = ctr + (size_t)g * 3;
  X1[t * 3 + 0] = (p[0] - c[0]) / 0.2f;
  X1[t * 3 + 1] = (p[1] - c[1]) / 0.2f;
  X1[t * 3 + 2] = (p[2] - c[2]) / 0.2f;
}

__global__ void group2_kernel(const float* __restrict__ xyz1,
                              const float* __restrict__ xyz2,
                              const float* __restrict__ f1,
                              const int* __restrict__ idx2,
                              float* __restrict__ X2) {
  const int t = blockIdx.x * 256 + threadIdx.x;
  if (t >= 65536 * 131) return;
  const int r = t / 131;
  const int c = t - r * 131;
  const int g = r >> 6;
  const int b = g >> 7;
  const int i = idx2[r];
  float v;
  if (c < 3) {
    v = (xyz1[((size_t)b * 512 + i) * 3 + c] - xyz2[(size_t)g * 3 + c]) / 0.4f;
  } else {
    v = f1[((size_t)b * 512 + i) * 128 + (c - 3)];
  }
  X2[t] = v;
}

__global__ void build_x3_kernel(const float* __restrict__ xyz2, const float* __restrict__ f2,
                                float* __restrict__ X3) {
  const int t = blockIdx.x * 256 + threadIdx.x;
  if (t >= 1024 * 259) return;
  const int r = t / 259;
  const int c = t - r * 259;
  X3[t] = (c < 3) ? xyz2[r * 3 + c] : f2[(size_t)r * 256 + (c - 3)];
}

// =====================================================================
// Fused head — float4 weight + LDS reads (R11, validated)
// =====================================================================
__global__ __launch_bounds__(512) void head_kernel(
    const float* __restrict__ gfeat, const float* __restrict__ objf,
    const float* __restrict__ w0, const float* __restrict__ b0,
    const float* __restrict__ w1, const float* __restrict__ b1,
    const float* __restrict__ w2, const float* __restrict__ b2,
    float* __restrict__ out) {
  __shared__ __align__(16) float comb[8 * 1152];
  __shared__ __align__(16) float h1[8 * 512];
  __shared__ __align__(16) float h2[8 * 256];
  const int tid = threadIdx.x;
  for (int i = tid; i < 8 * 1152; i += 512) {
    const int b = i / 1152, c = i - b * 1152;
    comb[i] = (c < 128) ? gfeat[b * 128 + c] : objf[b * 1024 + (c - 128)];
  }
  __syncthreads();
  for (int c = tid; c < 1152; c += 512) {
    float s = 0.f;
#pragma unroll
    for (int b = 0; b < 8; ++b) s += comb[b * 1152 + c];
    const float m = s * 0.125f;
    float v = 0.f;
#pragma unroll
    for (int b = 0; b < 8; ++b) { const float d = comb[b * 1152 + c] - m; v = fmaf(d, d, v); }
    const float sc = rsqrtf(v * 0.125f + EPS_BN);
#pragma unroll
    for (int b = 0; b < 8; ++b) comb[b * 1152 + c] = (comb[b * 1152 + c] - m) * sc;
  }
  __syncthreads();
  {  // layer 0: 1152 -> 512, float4 over k
    float a[8];
#pragma unroll
    for (int b = 0; b < 8; ++b) a[b] = b0[tid];
    const float* wr = w0 + (size_t)tid * 1152;
    for (int ci = 0; ci < 1152; ci += 4) {
      const float4 wv = *(const float4*)(wr + ci);
#pragma unroll
      for (int b = 0; b < 8; ++b) {
        const float4 xv = *(const float4*)(&comb[b * 1152 + ci]);
        a[b] = fmaf(xv.x, wv.x, a[b]);
        a[b] = fmaf(xv.y, wv.y, a[b]);
        a[b] = fmaf(xv.z, wv.z, a[b]);
        a[b] = fmaf(xv.w, wv.w, a[b]);
      }
    }
    float s = 0.f;
#pragma unroll
    for (int b = 0; b < 8; ++b) s += a[b];
    const float m = s * 0.125f;
    float v = 0.f;
#pragma unroll
    for (int b = 0; b < 8; ++b) { const float d = a[b] - m; v = fmaf(d, d, v); }
    const float sc = rsqrtf(v * 0.125f + EPS_BN);
#pragma unroll
    for (int b = 0; b < 8; ++b) h1[b * 512 + tid] = fmaxf(0.f, (a[b] - m) * sc);
  }
  __syncthreads();
  if (tid < 256) {  // layer 1: 512 -> 256, float4 over k
    float a[8];
#pragma unroll
    for (int b = 0; b < 8; ++b) a[b] = b1[tid];
    const float* wr = w1 + (size_t)tid * 512;
    for (int ci = 0; ci < 512; ci += 4) {
      const float4 wv = *(const float4*)(wr + ci);
#pragma unroll
      for (int b = 0; b < 8; ++b) {
        const float4 xv = *(const float4*)(&h1[b * 512 + ci]);
        a[b] = fmaf(xv.x, wv.x, a[b]);
        a[b] = fmaf(xv.y, wv.y, a[b]);
        a[b] = fmaf(xv.z, wv.z, a[b]);
        a[b] = fmaf(xv.w, wv.w, a[b]);
      }
    }
    float s = 0.f;
#pragma unroll
    for (int b = 0; b < 8; ++b) s += a[b];
    const float m = s * 0.125f;
    float v = 0.f;
#pragma unroll
    for (int b = 0; b < 8; ++b) { const float d = a[b] - m; v = fmaf(d, d, v); }
    const float sc = rsqrtf(v * 0.125f + EPS_BN);
#pragma unroll
    for (int b = 0; b < 8; ++b) h2[b * 256 + tid] = fmaxf(0.f, (a[b] - m) * sc);
  }
  __syncthreads();
  if (tid < 8) {  // layer 2: 256 -> 1, relu
    float s = b2[0];
    for (int ci = 0; ci < 256; ++ci) s = fmaf(h2[tid * 256 + ci], w2[ci], s);
    out[tid] = fmaxf(0.f, s);
  }
}

// =====================================================================
// Host orchestration
// =====================================================================
extern "C" void kernel_launch(void* const* d_in, const int* in_sizes, int n_in,
                              void* d_out, int out_size, void* d_ws, size_t ws_size,
                              hipStream_t stream) {
  (void)in_sizes; (void)n_in; (void)out_size; (void)ws_size;
  const float* obj  = (const float*)d_in[0];
  const float* grip = (const float*)d_in[1];
  const float* s1w0 = (const float*)d_in[2];
  const float* s1w1 = (const float*)d_in[3];
  const float* s1w2 = (const float*)d_in[4];
  const float* s2w0 = (const float*)d_in[5];
  const float* s2w1 = (const float*)d_in[6];
  const float* s2w2 = (const float*)d_in[7];
  const float* s3w0 = (const float*)d_in[8];
  const float* s3w1 = (const float*)d_in[9];
  const float* s3w2 = (const float*)d_in[10];
  const float* gw0  = (const float*)d_in[11];
  const float* gw1  = (const float*)d_in[12];
  const float* gw2  = (const float*)d_in[13];
  const float* hw0  = (const float*)d_in[14];
  const float* hb0  = (const float*)d_in[15];
  const float* hw1  = (const float*)d_in[16];
  const float* hb1  = (const float*)d_in[17];
  const float* hw2  = (const float*)d_in[18];
  const float* hb2  = (const float*)d_in[19];
  float* out = (float*)d_out;

  // ---- workspace layout (float offsets); total 26,658,304 floats ----
  float* wsf   = (float*)d_ws;
  float* stats = wsf;
  float* xyz1  = wsf + 23040;
  float* xyz2  = wsf + 35328;
  float* gfeat = wsf + 38400;
  float* objf  = wsf + 39424;
  float* f1    = wsf + 47616;
  float* f2    = wsf + 571904;
  float* x3    = wsf + 834048;
  int*   idx1  = (int*)(wsf + 1099264);
  int*   idx2  = (int*)(wsf + 1230336);
  float* bufP  = wsf + 1295872;
  float* bufQ  = wsf + 18073088;

  static const int st_off[12] = {0, 512, 1536, 2560, 3072, 3584,
                                 4608, 5632, 6656, 8704, 10752, 14848};
  auto st = [&](int li) { return stats + st_off[li]; };

  hipMemsetAsync(stats, 0, 23040 * sizeof(float), stream);

  auto gemm0 = [&](const float* X, const float* Wm, float* Y, int R, int Cin, int Cout,
                   int lo) {
    dim3 g((R + 127) / 128, (Cout + 127) / 128);
    gemm_xwt<false><<<g, 256, 0, stream>>>(X, Wm, Y, R, Cin, Cout, nullptr, 0, st(lo));
  };
  auto gemmf = [&](const float* X, const float* Wm, float* Y, int R, int Cin, int Cout,
                   int li, int lo) {
    dim3 g((R + 127) / 128, (Cout + 127) / 128);
    gemm_xwt<true><<<g, 256, 0, stream>>>(X, Wm, Y, R, Cin, Cout, st(li), R, st(lo));
  };
  auto applymax_k = [&](const float* Y, int li, int G, int ns, int C, float* o) {
    const int n = G * C;
    bn_apply_relu_maxpool<<<(n + 255) / 256, 256, 0, stream>>>(Y, st(li), o, G, ns, C);
  };

  // ---- SA1 FPS: sort (bufP is free until the gripper chain) + pruned scan ----
  float4* sorted = (float4*)bufP;  // 8*20480 float4 = 655,360 floats << bufP
  fps_sort_kernel<<<8, 1024, 0, stream>>>(obj, sorted);
  fps_sa1_kernel<<<8, 1024, 0, stream>>>(obj, sorted, xyz1);

  // ---- gripper encoder: [8,512,3] -> 64 -> 128 -> 128 -> maxpool ----
  float* gY1 = bufP;
  float* gY2 = bufP + 262144;
  float* gY3 = bufP + 786432;
  gemm0(grip, gw0, gY1, 4096, 3, 64, 0);
  gemmf(gY1, gw1, gY2, 4096, 64, 128, 0, 1);
  gemmf(gY2, gw2, gY3, 4096, 128, 128, 1, 2);
  applymax_k(gY3, 2, 8, 512, 128, gfeat);

  // ---- SA1: ball r=0.2 ns=32 (wave-per-center), MLP 3->64->64->128 ----
  ballquery_wave_kernel<20000, 32><<<1024, 256, 0, stream>>>(xyz1, obj, idx1, 4096, 512, 0.04f);
  float* X1 = bufQ;
  group1_kernel<<<512, 256, 0, stream>>>(obj, xyz1, idx1, X1);
  gemm0(X1, s1w0, bufP, 131072, 3, 64, 3);
  gemmf(bufP, s1w1, bufQ, 131072, 64, 64, 3, 4);
  gemmf(bufQ, s1w2, bufP, 131072, 64, 128, 4, 5);
  applymax_k(bufP, 5, 4096, 32, 128, f1);

  // ---- SA2: FPS 512->128, ball r=0.4 ns=64, MLP 131->128->128->256 ----
  fps2_kernel<512, 128, 256, 2><<<8, 256, 0, stream>>>(xyz1, xyz2);
  ballquery_wave_kernel<512, 64><<<256, 256, 0, stream>>>(xyz2, xyz1, idx2, 1024, 128, 0.16f);
  float* X2 = bufQ;
  group2_kernel<<<(65536 * 131 + 255) / 256, 256, 0, stream>>>(xyz1, xyz2, f1, idx2, X2);
  gemm0(X2, s2w0, bufP, 65536, 131, 128, 6);
  gemmf(bufP, s2w1, bufQ, 65536, 128, 128, 6, 7);
  gemmf(bufQ, s2w2, bufP, 65536, 128, 256, 7, 8);
  applymax_k(bufP, 8, 1024, 64, 256, f2);

  // ---- SA3 (group_all): concat[xyz2,f2] -> 256 -> 512 -> 1024 -> maxpool ----
  build_x3_kernel<<<(1024 * 259 + 255) / 256, 256, 0, stream>>>(xyz2, f2, x3);
  float* Y3a = bufQ;
  float* Y3b = bufQ + 262144;
  float* Y3c = bufQ + 786432;
  gemm0(x3, s3w0, Y3a, 1024, 259, 256, 9);
  gemmf(Y3a, s3w1, Y3b, 1024, 256, 512, 9, 10);
  gemmf(Y3b, s3w2, Y3c, 1024, 512, 1024, 10, 11);
  applymax_k(Y3c, 11, 8, 128, 1024, objf);

  // ---- head ----
  head_kernel<<<1, 512, 0, stream>>>(gfeat, objf, hw0, hb0, hw1, hb1, hw2, hb2, out);
}

// Round 13
// 2769.316 us; speedup vs baseline: 1.0892x; 1.0892x over previous
//
#include <hip/hip_runtime.h>
#include <cstddef>
#include <cstdint>

#define EPS_BN 1e-5f
#define NBINS 4
#define NEG_INF (-__builtin_inff())

// =====================================================================
// Tiled fp32 GEMM:  Y[r][o] = sum_ci X'[r][ci] * W[o][ci]   (Y = X' W^T)
// 128x128 tile, BK=16, 256 threads, 8x8 microtile/thread (split
// quadrants, <=2-way LDS reads). R multiple of 128; Cout guarded.
// FUSE_IN: X' = relu((X - mean)*scale) from st_in bins (prev layer BN).
// Epilogue: per-column sum/sumsq accumulated into st_out bins.
// =====================================================================
template <bool FUSE_IN>
__global__ __launch_bounds__(256) void gemm_xwt(const float* __restrict__ X,
                                                const float* __restrict__ Wm,
                                                float* __restrict__ Y,
                                                int R, int Cin, int Cout,
                                                const float* __restrict__ st_in, int Rin,
                                                float* __restrict__ st_out) {
  __shared__ __align__(16) float Xs[16][132];
  __shared__ __align__(16) float Ws[16][132];
  __shared__ float sMean[512], sScale[512];
  const int t  = threadIdx.x;
  const int r0 = blockIdx.x << 7;
  const int n0 = blockIdx.y << 7;
  const int tx = t & 15;
  const int ty = t >> 4;

  if constexpr (FUSE_IN) {
    const float inv = 1.f / (float)Rin;
    for (int k = t; k < Cin; k += 256) {
      float s = 0.f, q = 0.f;
#pragma unroll
      for (int bn = 0; bn < NBINS; ++bn) {
        s += st_in[bn * 2 * Cin + k];
        q += st_in[bn * 2 * Cin + Cin + k];
      }
      const float m  = s * inv;
      const float vr = fmaf(-m, m, q * inv);
      sMean[k]  = m;
      sScale[k] = rsqrtf(vr + EPS_BN);
    }
    __syncthreads();
  }

  float acc[8][8] = {};
  const int rStage = t >> 1;
  const int kBase  = (t & 1) << 3;
  const int nr     = n0 + rStage;

  for (int k0 = 0; k0 < Cin; k0 += 16) {
    const float* xrow = X  + (size_t)(r0 + rStage) * Cin + k0 + kBase;
    const float* wrow = Wm + (size_t)nr * Cin + k0 + kBase;
    if (((Cin & 3) == 0) && (k0 + 16 <= Cin)) {
      float4 xa = *(const float4*)(xrow);
      float4 xb = *(const float4*)(xrow + 4);
      if constexpr (FUSE_IN) {
        const int kb = k0 + kBase;
        xa.x = fmaxf(0.f, (xa.x - sMean[kb + 0]) * sScale[kb + 0]);
        xa.y = fmaxf(0.f, (xa.y - sMean[kb + 1]) * sScale[kb + 1]);
        xa.z = fmaxf(0.f, (xa.z - sMean[kb + 2]) * sScale[kb + 2]);
        xa.w = fmaxf(0.f, (xa.w - sMean[kb + 3]) * sScale[kb + 3]);
        xb.x = fmaxf(0.f, (xb.x - sMean[kb + 4]) * sScale[kb + 4]);
        xb.y = fmaxf(0.f, (xb.y - sMean[kb + 5]) * sScale[kb + 5]);
        xb.z = fmaxf(0.f, (xb.z - sMean[kb + 6]) * sScale[kb + 6]);
        xb.w = fmaxf(0.f, (xb.w - sMean[kb + 7]) * sScale[kb + 7]);
      }
      Xs[kBase + 0][rStage] = xa.x; Xs[kBase + 1][rStage] = xa.y;
      Xs[kBase + 2][rStage] = xa.z; Xs[kBase + 3][rStage] = xa.w;
      Xs[kBase + 4][rStage] = xb.x; Xs[kBase + 5][rStage] = xb.y;
      Xs[kBase + 6][rStage] = xb.z; Xs[kBase + 7][rStage] = xb.w;
      float4 wa = {0, 0, 0, 0}, wb = {0, 0, 0, 0};
      if (nr < Cout) { wa = *(const float4*)(wrow); wb = *(const float4*)(wrow + 4); }
      Ws[kBase + 0][rStage] = wa.x; Ws[kBase + 1][rStage] = wa.y;
      Ws[kBase + 2][rStage] = wa.z; Ws[kBase + 3][rStage] = wa.w;
      Ws[kBase + 4][rStage] = wb.x; Ws[kBase + 5][rStage] = wb.y;
      Ws[kBase + 6][rStage] = wb.z; Ws[kBase + 7][rStage] = wb.w;
    } else {
#pragma unroll
      for (int u = 0; u < 8; ++u) {
        const int k = k0 + kBase + u;
        float xe = 0.f, we = 0.f;
        if (k < Cin) {
          xe = xrow[u];
          if constexpr (FUSE_IN) xe = fmaxf(0.f, (xe - sMean[k]) * sScale[k]);
          if (nr < Cout) we = wrow[u];
        }
        Xs[kBase + u][rStage] = xe;
        Ws[kBase + u][rStage] = we;
      }
    }
    __syncthreads();
#pragma unroll
    for (int kk = 0; kk < 16; ++kk) {
      const float4 a0 = *(const float4*)(&Xs[kk][ty << 2]);
      const float4 a1 = *(const float4*)(&Xs[kk][64 + (ty << 2)]);
      const float4 b0 = *(const float4*)(&Ws[kk][tx << 2]);
      const float4 b1 = *(const float4*)(&Ws[kk][64 + (tx << 2)]);
      const float av[8] = {a0.x, a0.y, a0.z, a0.w, a1.x, a1.y, a1.z, a1.w};
      const float bw[8] = {b0.x, b0.y, b0.z, b0.w, b1.x, b1.y, b1.z, b1.w};
#pragma unroll
      for (int i = 0; i < 8; ++i)
#pragma unroll
        for (int j = 0; j < 8; ++j) acc[i][j] = fmaf(av[i], bw[j], acc[i][j]);
    }
    __syncthreads();
  }
#pragma unroll
  for (int h = 0; h < 2; ++h)
#pragma unroll
    for (int i = 0; i < 4; ++i) {
      const int r = r0 + h * 64 + (ty << 2) + i;
      float* yr = Y + (size_t)r * Cout;
#pragma unroll
      for (int g = 0; g < 2; ++g) {
        const int n = n0 + g * 64 + (tx << 2);
        if (n < Cout) {
          float4 o = {acc[h * 4 + i][g * 4 + 0], acc[h * 4 + i][g * 4 + 1],
                      acc[h * 4 + i][g * 4 + 2], acc[h * 4 + i][g * 4 + 3]};
          *(float4*)(yr + n) = o;
        }
      }
    }
#pragma unroll
  for (int g = 0; g < 2; ++g)
#pragma unroll
    for (int j = 0; j < 4; ++j) {
      float s = 0.f, q = 0.f;
#pragma unroll
      for (int rh = 0; rh < 8; ++rh) {
        const float v = acc[rh][g * 4 + j];
        s += v;
        q = fmaf(v, v, q);
      }
      Xs[ty][g * 64 + (tx << 2) + j] = s;
      Ws[ty][g * 64 + (tx << 2) + j] = q;
    }
  __syncthreads();
  if (t < 128) {
    const int n = n0 + t;
    if (n < Cout) {
      float s = 0.f, q = 0.f;
#pragma unroll
      for (int w = 0; w < 16; ++w) { s += Xs[w][t]; q += Ws[w][t]; }
      float* dst = st_out + (blockIdx.x & (NBINS - 1)) * 2 * Cout;
      atomicAdd(dst + n, s);
      atomicAdd(dst + Cout + n, q);
    }
  }
}

// normalize -> relu -> max over ns rows per group
__global__ void bn_apply_relu_maxpool(const float* __restrict__ Y,
                                      const float* __restrict__ st,
                                      float* __restrict__ o, int G, int ns, int C) {
  const int i = blockIdx.x * 256 + threadIdx.x;
  if (i >= G * C) return;
  const int c = i % C;
  const int g = i / C;
  float s = 0.f, q = 0.f;
#pragma unroll
  for (int bn = 0; bn < NBINS; ++bn) {
    s += st[bn * 2 * C + c];
    q += st[bn * 2 * C + C + c];
  }
  const int R = G * ns;
  const float inv = 1.f / (float)R;
  const float m  = s * inv;
  const float vr = fmaf(-m, m, q * inv);
  const float sc = rsqrtf(vr + EPS_BN);
  const float* p = Y + (size_t)g * ns * C + c;
  float mx = NEG_INF;
  for (int k = 0; k < ns; ++k) mx = fmaxf(mx, p[(size_t)k * C]);
  o[i] = fmaxf(0.f, (mx - m) * sc);
}

// =====================================================================
// FPS SA1 (20000 -> 512) v7 — DENSE scan (prune is dead: R6/R7/R9/R12
// all lost; with a per-step block barrier, per-step cost = max over
// waves and some wave always rescans). v7 keeps R5's dense structure
// and applies two bounded micro-opts:
//  (a) contiguous ownership: thread owns 20 consecutive points; the 12
//      streamed ones are read as 9 aligned dwordx4 (vs 36 scalar
//      dwords) — same values, ascending index order preserved.
//  (b) 1-barrier reduce with parity slots (R9-HW-validated, WAR-safe):
//      owner lane writes packed (v,idx)+coords; after ONE barrier all
//      threads combine 16 broadcast slots (~19 DS ops) instead of
//      idling behind wave0's dependent stage-2 butterfly + 2nd barrier.
// Math unchanged: rn op tree, exact fminf, first-orig-index tie-break.
// Threads 1000..1023 are fully out-of-range: base clamped to p, dd=-inf
// (never win). LDS: 48K dd + 0.64K slots.
// =====================================================================
#define REPB7(X) X(12) X(13) X(14) X(15) X(16) X(17) X(18) X(19)

__global__ __launch_bounds__(1024)
void fps_sa1_kernel(const float* __restrict__ xyz, float* __restrict__ new_xyz) {
  const int b    = blockIdx.x;
  const int tid  = threadIdx.x;
  const int wave = tid >> 6;  // 0..15
  const float* p = xyz + (size_t)b * 20000 * 3;
  const bool real = (tid < 1000);          // owns points [tid*20, tid*20+20)
  const int  base = real ? tid * 20 : 0;   // clamped for OOB threads
  const float4* sp4 = (const float4*)(p + (size_t)base * 3);  // 16B-aligned

  __shared__ float ddL[12 * 1024];               // 48 KB, [slot][tid]
  __shared__ __align__(8) float2 sVI[2][16];     // parity x wave: (v, bitcast idx)
  __shared__ float sxw[2][16], syw[2][16], szw[2][16];

  // register-resident slots k=12..19
#define DECLR(k) float px##k, py##k, pz##k, dd##k;
  REPB7(DECLR)
#undef DECLR

  for (int j = 0; j < 12; ++j) ddL[j * 1024 + tid] = real ? 1e10f : NEG_INF;
#define INITR(k) {                                                          \
    const int i = base + (k);                                               \
    px##k = p[i * 3 + 0]; py##k = p[i * 3 + 1]; pz##k = p[i * 3 + 2];       \
    dd##k = real ? 1e10f : NEG_INF; }
  REPB7(INITR)
#undef INITR

  float fx = p[0], fy = p[1], fz = p[2];
  if (tid == 0) {
    float* o = new_xyz + (size_t)b * 512 * 3;
    o[0] = fx; o[1] = fy; o[2] = fz;
  }
  __syncthreads();

  for (int s = 1; s < 512; ++s) {
    const int par = s & 1;
    float bv = NEG_INF;
    int   bi = 0x7fffffff;
    float bx = 0.f, by = 0.f, bz = 0.f;
    // streamed region: 3 groups x (3 float4 = 4 points), ascending order
#pragma unroll
    for (int g = 0; g < 3; ++g) {
      const float4 qa = sp4[g * 3 + 0];
      const float4 qb = sp4[g * 3 + 1];
      const float4 qc = sp4[g * 3 + 2];
#define PROC(jj, QX, QY, QZ) {                                              \
      const int j = g * 4 + (jj);                                           \
      const float dx = (QX) - fx, dy = (QY) - fy, dz = (QZ) - fz;           \
      const float d = __fadd_rn(__fadd_rn(__fmul_rn(dx, dx), __fmul_rn(dy, dy)), \
                                __fmul_rn(dz, dz));                         \
      const int a = j * 1024 + tid;                                         \
      const float nd = fminf(ddL[a], d);                                    \
      ddL[a] = nd;                                                          \
      if (nd > bv) { bv = nd; bi = base + j; bx = (QX); by = (QY); bz = (QZ); } }
      PROC(0, qa.x, qa.y, qa.z)
      PROC(1, qa.w, qb.x, qb.y)
      PROC(2, qb.z, qb.w, qc.x)
      PROC(3, qc.y, qc.z, qc.w)
#undef PROC
    }
    // register region (indices base+12..base+19, ascending)
#define SCANR(k) {                                                          \
    const float dx = px##k - fx, dy = py##k - fy, dz = pz##k - fz;          \
    const float d  = __fadd_rn(__fadd_rn(__fmul_rn(dx, dx), __fmul_rn(dy, dy)), \
                               __fmul_rn(dz, dz));                          \
    const float nd = fminf(dd##k, d);                                       \
    dd##k = nd;                                                             \
    if (nd > bv) { bv = nd; bi = base + (k);                                \
                   bx = px##k; by = py##k; bz = pz##k; } }
    REPB7(SCANR)
#undef SCANR
    // wave butterfly on (value, index); owner = lane whose bi wins
    float v  = bv;
    int   i0 = bi;
#pragma unroll
    for (int m = 1; m < 64; m <<= 1) {
      const float ov = __shfl_xor(v, m, 64);
      const int   oi = __shfl_xor(i0, m, 64);
      if (ov > v || (ov == v && oi < i0)) { v = ov; i0 = oi; }
    }
    if (i0 == bi) {  // unique owner (disjoint index sets per lane)
      float2 e; e.x = bv; e.y = __int_as_float(bi);
      sVI[par][wave] = e;
      sxw[par][wave] = bx; syw[par][wave] = by; szw[par][wave] = bz;
    }
    __syncthreads();
    // all threads combine the 16 wave winners (broadcast b64 reads)
    int ww = 0;
    {
      float2 e = sVI[par][0];
      float wv = e.x;
      int   wi = __float_as_int(e.y);
#pragma unroll
      for (int w = 1; w < 16; ++w) {
        e = sVI[par][w];
        const int ei = __float_as_int(e.y);
        if (e.x > wv || (e.x == wv && ei < wi)) { wv = e.x; wi = ei; ww = w; }
      }
    }
    fx = sxw[par][ww]; fy = syw[par][ww]; fz = szw[par][ww];
    if (tid == 0) {
      float* o = new_xyz + ((size_t)b * 512 + s) * 3;
      o[0] = fx; o[1] = fy; o[2] = fz;
    }
    // parity slots make a second barrier unnecessary (R9-validated):
    // writes to slot[par] at step s+2 occur after barrier_{s+1}, which
    // all step-s readers have already reached.
  }
}

// =====================================================================
// FPS small (SA2: 512 -> 128), one block per batch, all state in regs.
// =====================================================================
template <int N, int NP, int THREADS, int NPT>
__global__ __launch_bounds__(THREADS)
void fps2_kernel(const float* __restrict__ xyz, float* __restrict__ new_xyz) {
  constexpr int NW = THREADS / 64;
  const int b    = blockIdx.x;
  const int tid  = threadIdx.x;
  const int lane = tid & 63;
  const int wave = tid >> 6;
  const float* p = xyz + (size_t)b * N * 3;
  float px[NPT], py[NPT], pz[NPT], dd[NPT];
#pragma unroll
  for (int j = 0; j < NPT; ++j) {
    const int i = tid + j * THREADS;
    if (i < N) {
      px[j] = p[i * 3 + 0];
      py[j] = p[i * 3 + 1];
      pz[j] = p[i * 3 + 2];
      dd[j] = 1e10f;
    } else {
      px[j] = 0.f; py[j] = 0.f; pz[j] = 0.f;
      dd[j] = NEG_INF;
    }
  }
  __shared__ float sv[NW], sx[NW], sy[NW], sz[NW];
  __shared__ int   si[NW];
  __shared__ float bc[3];
  float fx = p[0], fy = p[1], fz = p[2];
  if (tid == 0) {
    float* o = new_xyz + (size_t)b * NP * 3;
    o[0] = fx; o[1] = fy; o[2] = fz;
  }
  for (int s = 1; s < NP; ++s) {
    float bv = NEG_INF;
    int   bi = 0x7fffffff;
    float bx = 0.f, by = 0.f, bz = 0.f;
#pragma unroll
    for (int j = 0; j < NPT; ++j) {
      const float dx = px[j] - fx;
      const float dy = py[j] - fy;
      const float dz = pz[j] - fz;
      const float d  = __fadd_rn(__fadd_rn(__fmul_rn(dx, dx), __fmul_rn(dy, dy)),
                                 __fmul_rn(dz, dz));
      const float nd = fminf(dd[j], d);
      dd[j] = nd;
      if (nd > bv) { bv = nd; bi = tid + j * THREADS; bx = px[j]; by = py[j]; bz = pz[j]; }
    }
    float v = bv;
    int   i0 = bi;
#pragma unroll
    for (int m = 1; m < 64; m <<= 1) {
      const float ov = __shfl_xor(v, m, 64);
      const int   oi = __shfl_xor(i0, m, 64);
      if (ov > v || (ov == v && oi < i0)) { v = ov; i0 = oi; }
    }
    if (i0 == bi) {
      sv[wave] = bv; si[wave] = bi; sx[wave] = bx; sy[wave] = by; sz[wave] = bz;
    }
    __syncthreads();
    if (tid < 64) {
      const float lv = (lane < NW) ? sv[lane] : NEG_INF;
      const int   li = (lane < NW) ? si[lane] : 0x7fffffff;
      float v2 = lv;
      int   i2 = li;
#pragma unroll
      for (int m = 1; m < NW; m <<= 1) {
        const float ov = __shfl_xor(v2, m, 64);
        const int   oi = __shfl_xor(i2, m, 64);
        if (ov > v2 || (ov == v2 && oi < i2)) { v2 = ov; i2 = oi; }
      }
      if (lane < NW && li == i2) {
        const float wx = sx[lane], wy = sy[lane], wz = sz[lane];
        bc[0] = wx; bc[1] = wy; bc[2] = wz;
        float* o = new_xyz + ((size_t)b * NP + s) * 3;
        o[0] = wx; o[1] = wy; o[2] = wz;
      }
    }
    __syncthreads();
    fx = bc[0]; fy = bc[1]; fz = bc[2];
  }
}

// =====================================================================
// Ball query: ONE WAVE PER CENTER, ballot + prefix-popcount (R11,
// validated). Emits the first NS qualifying indices in ascending order.
// =====================================================================
template <int N, int NS>
__global__ __launch_bounds__(256)
void ballquery_wave_kernel(const float* __restrict__ centers,
                           const float* __restrict__ pts,
                           int* __restrict__ idx, int BS, int S, float r2) {
  const int w    = (blockIdx.x * 256 + threadIdx.x) >> 6;  // global wave id
  const int lane = threadIdx.x & 63;
  if (w >= BS) return;
  const int b = w / S;
  const float cx = centers[w * 3 + 0];
  const float cy = centers[w * 3 + 1];
  const float cz = centers[w * 3 + 2];
  const float* p = pts + (size_t)b * N * 3;
  int* o = idx + (size_t)w * NS;
  int total = 0;
  int first = -1;
  for (int i0 = 0; i0 < N && total < NS; i0 += 64) {
    const int i = i0 + lane;
    bool pred = false;
    if (i < N) {
      const float dx = cx - p[i * 3 + 0];
      const float dy = cy - p[i * 3 + 1];
      const float dz = cz - p[i * 3 + 2];
      const float d2 = __fadd_rn(__fadd_rn(__fmul_rn(dx, dx), __fmul_rn(dy, dy)),
                                 __fmul_rn(dz, dz));
      pred = (d2 < r2);
    }
    const unsigned long long mask = __ballot(pred);
    if (mask) {
      const unsigned long long below = (lane == 0) ? 0ull : (mask << (64 - lane));
      const int before = __popcll(below);
      if (pred && (total + before) < NS) o[total + before] = i;
      if (first < 0) first = i0 + (__ffsll((long long)mask) - 1);  // wave-uniform
      total += __popcll(mask);
    }
  }
  if (lane >= total && lane < NS) o[lane] = first;
}

// =====================================================================
// Grouping / concat kernels
// =====================================================================
__global__ void group1_kernel(const float* __restrict__ xyz, const float* __restrict__ ctr,
                              const int* __restrict__ idx, float* __restrict__ X1) {
  const int t = blockIdx.x * 256 + threadIdx.x;
  if (t >= 8 * 512 * 32) return;
  const int g = t >> 5;
  const int b = g >> 9;
  const int i = idx[t];
  const float* p = xyz + ((size_t)b * 20000 + i) * 3;
  const float* c = ctr + (size_t)g * 3;
  X1[t * 3 + 0] = (p[0] - c[0]) / 0.2f;
  X1[t * 3 + 1] = (p[1] - c[1]) / 0.2f;
  X1[t * 3 + 2] = (p[2] - c[2]) / 0.2f;
}

__global__ void group2_kernel(const float* __restrict__ xyz1,
                              const float* __restrict__ xyz2,
                              const float* __restrict__ f1,
                              const int* __restrict__ idx2,
                              float* __restrict__ X2) {
  const int t = blockIdx.x * 256 + threadIdx.x;
  if (t >= 65536 * 131) return;
  const int r = t / 131;
  const int c = t - r * 131;
  const int g = r >> 6;
  const int b = g >> 7;
  const int i = idx2[r];
  float v;
  if (c < 3) {
    v = (xyz1[((size_t)b * 512 + i) * 3 + c] - xyz2[(size_t)g * 3 + c]) / 0.4f;
  } else {
    v = f1[((size_t)b * 512 + i) * 128 + (c - 3)];
  }
  X2[t] = v;
}

__global__ void build_x3_kernel(const float* __restrict__ xyz2, const float* __restrict__ f2,
                                float* __restrict__ X3) {
  const int t = blockIdx.x * 256 + threadIdx.x;
  if (t >= 1024 * 259) return;
  const int r = t / 259;
  const int c = t - r * 259;
  X3[t] = (c < 3) ? xyz2[r * 3 + c] : f2[(size_t)r * 256 + (c - 3)];
}

// =====================================================================
// Fused head — float4 weight + LDS reads (R11, validated)
// =====================================================================
__global__ __launch_bounds__(512) void head_kernel(
    const float* __restrict__ gfeat, const float* __restrict__ objf,
    const float* __restrict__ w0, const float* __restrict__ b0,
    const float* __restrict__ w1, const float* __restrict__ b1,
    const float* __restrict__ w2, const float* __restrict__ b2,
    float* __restrict__ out) {
  __shared__ __align__(16) float comb[8 * 1152];
  __shared__ __align__(16) float h1[8 * 512];
  __shared__ __align__(16) float h2[8 * 256];
  const int tid = threadIdx.x;
  for (int i = tid; i < 8 * 1152; i += 512) {
    const int b = i / 1152, c = i - b * 1152;
    comb[i] = (c < 128) ? gfeat[b * 128 + c] : objf[b * 1024 + (c - 128)];
  }
  __syncthreads();
  for (int c = tid; c < 1152; c += 512) {
    float s = 0.f;
#pragma unroll
    for (int b = 0; b < 8; ++b) s += comb[b * 1152 + c];
    const float m = s * 0.125f;
    float v = 0.f;
#pragma unroll
    for (int b = 0; b < 8; ++b) { const float d = comb[b * 1152 + c] - m; v = fmaf(d, d, v); }
    const float sc = rsqrtf(v * 0.125f + EPS_BN);
#pragma unroll
    for (int b = 0; b < 8; ++b) comb[b * 1152 + c] = (comb[b * 1152 + c] - m) * sc;
  }
  __syncthreads();
  {  // layer 0: 1152 -> 512, float4 over k
    float a[8];
#pragma unroll
    for (int b = 0; b < 8; ++b) a[b] = b0[tid];
    const float* wr = w0 + (size_t)tid * 1152;
    for (int ci = 0; ci < 1152; ci += 4) {
      const float4 wv = *(const float4*)(wr + ci);
#pragma unroll
      for (int b = 0; b < 8; ++b) {
        const float4 xv = *(const float4*)(&comb[b * 1152 + ci]);
        a[b] = fmaf(xv.x, wv.x, a[b]);
        a[b] = fmaf(xv.y, wv.y, a[b]);
        a[b] = fmaf(xv.z, wv.z, a[b]);
        a[b] = fmaf(xv.w, wv.w, a[b]);
      }
    }
    float s = 0.f;
#pragma unroll
    for (int b = 0; b < 8; ++b) s += a[b];
    const float m = s * 0.125f;
    float v = 0.f;
#pragma unroll
    for (int b = 0; b < 8; ++b) { const float d = a[b] - m; v = fmaf(d, d, v); }
    const float sc = rsqrtf(v * 0.125f + EPS_BN);
#pragma unroll
    for (int b = 0; b < 8; ++b) h1[b * 512 + tid] = fmaxf(0.f, (a[b] - m) * sc);
  }
  __syncthreads();
  if (tid < 256) {  // layer 1: 512 -> 256, float4 over k
    float a[8];
#pragma unroll
    for (int b = 0; b < 8; ++b) a[b] = b1[tid];
    const float* wr = w1 + (size_t)tid * 512;
    for (int ci = 0; ci < 512; ci += 4) {
      const float4 wv = *(const float4*)(wr + ci);
#pragma unroll
      for (int b = 0; b < 8; ++b) {
        const float4 xv = *(const float4*)(&h1[b * 512 + ci]);
        a[b] = fmaf(xv.x, wv.x, a[b]);
        a[b] = fmaf(xv.y, wv.y, a[b]);
        a[b] = fmaf(xv.z, wv.z, a[b]);
        a[b] = fmaf(xv.w, wv.w, a[b]);
      }
    }
    float s = 0.f;
#pragma unroll
    for (int b = 0; b < 8; ++b) s += a[b];
    const float m = s * 0.125f;
    float v = 0.f;
#pragma unroll
    for (int b = 0; b < 8; ++b) { const float d = a[b] - m; v = fmaf(d, d, v); }
    const float sc = rsqrtf(v * 0.125f + EPS_BN);
#pragma unroll
    for (int b = 0; b < 8; ++b) h2[b * 256 + tid] = fmaxf(0.f, (a[b] - m) * sc);
  }
  __syncthreads();
  if (tid < 8) {  // layer 2: 256 -> 1, relu
    float s = b2[0];
    for (int ci = 0; ci < 256; ++ci) s = fmaf(h2[tid * 256 + ci], w2[ci], s);
    out[tid] = fmaxf(0.f, s);
  }
}

// =====================================================================
// Host orchestration
// =====================================================================
extern "C" void kernel_launch(void* const* d_in, const int* in_sizes, int n_in,
                              void* d_out, int out_size, void* d_ws, size_t ws_size,
                              hipStream_t stream) {
  (void)in_sizes; (void)n_in; (void)out_size; (void)ws_size;
  const float* obj  = (const float*)d_in[0];
  const float* grip = (const float*)d_in[1];
  const float* s1w0 = (const float*)d_in[2];
  const float* s1w1 = (const float*)d_in[3];
  const float* s1w2 = (const float*)d_in[4];
  const float* s2w0 = (const float*)d_in[5];
  const float* s2w1 = (const float*)d_in[6];
  const float* s2w2 = (const float*)d_in[7];
  const float* s3w0 = (const float*)d_in[8];
  const float* s3w1 = (const float*)d_in[9];
  const float* s3w2 = (const float*)d_in[10];
  const float* gw0  = (const float*)d_in[11];
  const float* gw1  = (const float*)d_in[12];
  const float* gw2  = (const float*)d_in[13];
  const float* hw0  = (const float*)d_in[14];
  const float* hb0  = (const float*)d_in[15];
  const float* hw1  = (const float*)d_in[16];
  const float* hb1  = (const float*)d_in[17];
  const float* hw2  = (const float*)d_in[18];
  const float* hb2  = (const float*)d_in[19];
  float* out = (float*)d_out;

  // ---- workspace layout (float offsets); total 26,658,304 floats ----
  float* wsf   = (float*)d_ws;
  float* stats = wsf;
  float* xyz1  = wsf + 23040;
  float* xyz2  = wsf + 35328;
  float* gfeat = wsf + 38400;
  float* objf  = wsf + 39424;
  float* f1    = wsf + 47616;
  float* f2    = wsf + 571904;
  float* x3    = wsf + 834048;
  int*   idx1  = (int*)(wsf + 1099264);
  int*   idx2  = (int*)(wsf + 1230336);
  float* bufP  = wsf + 1295872;
  float* bufQ  = wsf + 18073088;

  static const int st_off[12] = {0, 512, 1536, 2560, 3072, 3584,
                                 4608, 5632, 6656, 8704, 10752, 14848};
  auto st = [&](int li) { return stats + st_off[li]; };

  hipMemsetAsync(stats, 0, 23040 * sizeof(float), stream);

  auto gemm0 = [&](const float* X, const float* Wm, float* Y, int R, int Cin, int Cout,
                   int lo) {
    dim3 g((R + 127) / 128, (Cout + 127) / 128);
    gemm_xwt<false><<<g, 256, 0, stream>>>(X, Wm, Y, R, Cin, Cout, nullptr, 0, st(lo));
  };
  auto gemmf = [&](const float* X, const float* Wm, float* Y, int R, int Cin, int Cout,
                   int li, int lo) {
    dim3 g((R + 127) / 128, (Cout + 127) / 128);
    gemm_xwt<true><<<g, 256, 0, stream>>>(X, Wm, Y, R, Cin, Cout, st(li), R, st(lo));
  };
  auto applymax_k = [&](const float* Y, int li, int G, int ns, int C, float* o) {
    const int n = G * C;
    bn_apply_relu_maxpool<<<(n + 255) / 256, 256, 0, stream>>>(Y, st(li), o, G, ns, C);
  };

  // ---- SA1 FPS (dense scan v7: float4 streaming + 1-barrier reduce) ----
  fps_sa1_kernel<<<8, 1024, 0, stream>>>(obj, xyz1);

  // ---- gripper encoder: [8,512,3] -> 64 -> 128 -> 128 -> maxpool ----
  float* gY1 = bufP;
  float* gY2 = bufP + 262144;
  float* gY3 = bufP + 786432;
  gemm0(grip, gw0, gY1, 4096, 3, 64, 0);
  gemmf(gY1, gw1, gY2, 4096, 64, 128, 0, 1);
  gemmf(gY2, gw2, gY3, 4096, 128, 128, 1, 2);
  applymax_k(gY3, 2, 8, 512, 128, gfeat);

  // ---- SA1: ball r=0.2 ns=32 (wave-per-center), MLP 3->64->64->128 ----
  ballquery_wave_kernel<20000, 32><<<1024, 256, 0, stream>>>(xyz1, obj, idx1, 4096, 512, 0.04f);
  float* X1 = bufQ;
  group1_kernel<<<512, 256, 0, stream>>>(obj, xyz1, idx1, X1);
  gemm0(X1, s1w0, bufP, 131072, 3, 64, 3);
  gemmf(bufP, s1w1, bufQ, 131072, 64, 64, 3, 4);
  gemmf(bufQ, s1w2, bufP, 131072, 64, 128, 4, 5);
  applymax_k(bufP, 5, 4096, 32, 128, f1);

  // ---- SA2: FPS 512->128, ball r=0.4 ns=64, MLP 131->128->128->256 ----
  fps2_kernel<512, 128, 256, 2><<<8, 256, 0, stream>>>(xyz1, xyz2);
  ballquery_wave_kernel<512, 64><<<256, 256, 0, stream>>>(xyz2, xyz1, idx2, 1024, 128, 0.16f);
  float* X2 = bufQ;
  group2_kernel<<<(65536 * 131 + 255) / 256, 256, 0, stream>>>(xyz1, xyz2, f1, idx2, X2);
  gemm0(X2, s2w0, bufP, 65536, 131, 128, 6);
  gemmf(bufP, s2w1, bufQ, 65536, 128, 128, 6, 7);
  gemmf(bufQ, s2w2, bufP, 65536, 128, 256, 7, 8);
  applymax_k(bufP, 8, 1024, 64, 256, f2);

  // ---- SA3 (group_all): concat[xyz2,f2] -> 256 -> 512 -> 1024 -> maxpool ----
  build_x3_kernel<<<(1024 * 259 + 255) / 256, 256, 0, stream>>>(xyz2, f2, x3);
  float* Y3a = bufQ;
  float* Y3b = bufQ + 262144;
  float* Y3c = bufQ + 786432;
  gemm0(x3, s3w0, Y3a, 1024, 259, 256, 9);
  gemmf(Y3a, s3w1, Y3b, 1024, 256, 512, 9, 10);
  gemmf(Y3b, s3w2, Y3c, 1024, 512, 1024, 10, 11);
  applymax_k(Y3c, 11, 8, 128, 1024, objf);

  // ---- head ----
  head_kernel<<<1, 512, 0, stream>>>(gfeat, objf, hw0, hb0, hw1, hb1, hw2, hb2, out);
}

// Round 14
// 2411.638 us; speedup vs baseline: 1.2508x; 1.1483x over previous
//
#include <hip/hip_runtime.h>
#include <cstddef>
#include <cstdint>

#define EPS_BN 1e-5f
#define NBINS 4
#define NEG_INF (-__builtin_inff())

// =====================================================================
// Tiled fp32 GEMM:  Y[r][o] = sum_ci X'[r][ci] * W[o][ci]   (Y = X' W^T)
// 128x128 tile, BK=16, 256 threads, 8x8 microtile/thread (split
// quadrants, <=2-way LDS reads). R multiple of 128; Cout guarded.
// FUSE_IN:  X' = relu((X - mean)*scale) from st_in bins (prev layer BN).
// FUSE_MAX: instead of storing Y, store per-(ns-group, col) max of raw Y
//           into pooled[G][Cout]. Valid because ns | 128 (each tile has
//           only complete groups) and grid.y column ranges are disjoint
//           -> exactly one block writes each pooled element, no atomics.
//           BN+relu applied later on the pooled value (monotone => same
//           result as reference, exact fmaxf).
// Epilogue always: per-column sum/sumsq of raw Y into st_out bins.
// =====================================================================
template <bool FUSE_IN, bool FUSE_MAX>
__global__ __launch_bounds__(256) void gemm_xwt(const float* __restrict__ X,
                                                const float* __restrict__ Wm,
                                                float* __restrict__ Y,
                                                int R, int Cin, int Cout,
                                                const float* __restrict__ st_in, int Rin,
                                                float* __restrict__ st_out,
                                                float* __restrict__ pooled, int ns) {
  __shared__ __align__(16) float Xs[16][132];
  __shared__ __align__(16) float Ws[16][132];
  __shared__ float sMean[512], sScale[512];
  const int t  = threadIdx.x;
  const int r0 = blockIdx.x << 7;
  const int n0 = blockIdx.y << 7;
  const int tx = t & 15;
  const int ty = t >> 4;

  if constexpr (FUSE_IN) {
    const float inv = 1.f / (float)Rin;
    for (int k = t; k < Cin; k += 256) {
      float s = 0.f, q = 0.f;
#pragma unroll
      for (int bn = 0; bn < NBINS; ++bn) {
        s += st_in[bn * 2 * Cin + k];
        q += st_in[bn * 2 * Cin + Cin + k];
      }
      const float m  = s * inv;
      const float vr = fmaf(-m, m, q * inv);
      sMean[k]  = m;
      sScale[k] = rsqrtf(vr + EPS_BN);
    }
    __syncthreads();
  }

  float acc[8][8] = {};
  const int rStage = t >> 1;
  const int kBase  = (t & 1) << 3;
  const int nr     = n0 + rStage;

  for (int k0 = 0; k0 < Cin; k0 += 16) {
    const float* xrow = X  + (size_t)(r0 + rStage) * Cin + k0 + kBase;
    const float* wrow = Wm + (size_t)nr * Cin + k0 + kBase;
    if (((Cin & 3) == 0) && (k0 + 16 <= Cin)) {
      float4 xa = *(const float4*)(xrow);
      float4 xb = *(const float4*)(xrow + 4);
      if constexpr (FUSE_IN) {
        const int kb = k0 + kBase;
        xa.x = fmaxf(0.f, (xa.x - sMean[kb + 0]) * sScale[kb + 0]);
        xa.y = fmaxf(0.f, (xa.y - sMean[kb + 1]) * sScale[kb + 1]);
        xa.z = fmaxf(0.f, (xa.z - sMean[kb + 2]) * sScale[kb + 2]);
        xa.w = fmaxf(0.f, (xa.w - sMean[kb + 3]) * sScale[kb + 3]);
        xb.x = fmaxf(0.f, (xb.x - sMean[kb + 4]) * sScale[kb + 4]);
        xb.y = fmaxf(0.f, (xb.y - sMean[kb + 5]) * sScale[kb + 5]);
        xb.z = fmaxf(0.f, (xb.z - sMean[kb + 6]) * sScale[kb + 6]);
        xb.w = fmaxf(0.f, (xb.w - sMean[kb + 7]) * sScale[kb + 7]);
      }
      Xs[kBase + 0][rStage] = xa.x; Xs[kBase + 1][rStage] = xa.y;
      Xs[kBase + 2][rStage] = xa.z; Xs[kBase + 3][rStage] = xa.w;
      Xs[kBase + 4][rStage] = xb.x; Xs[kBase + 5][rStage] = xb.y;
      Xs[kBase + 6][rStage] = xb.z; Xs[kBase + 7][rStage] = xb.w;
      float4 wa = {0, 0, 0, 0}, wb = {0, 0, 0, 0};
      if (nr < Cout) { wa = *(const float4*)(wrow); wb = *(const float4*)(wrow + 4); }
      Ws[kBase + 0][rStage] = wa.x; Ws[kBase + 1][rStage] = wa.y;
      Ws[kBase + 2][rStage] = wa.z; Ws[kBase + 3][rStage] = wa.w;
      Ws[kBase + 4][rStage] = wb.x; Ws[kBase + 5][rStage] = wb.y;
      Ws[kBase + 6][rStage] = wb.z; Ws[kBase + 7][rStage] = wb.w;
    } else {
#pragma unroll
      for (int u = 0; u < 8; ++u) {
        const int k = k0 + kBase + u;
        float xe = 0.f, we = 0.f;
        if (k < Cin) {
          xe = xrow[u];
          if constexpr (FUSE_IN) xe = fmaxf(0.f, (xe - sMean[k]) * sScale[k]);
          if (nr < Cout) we = wrow[u];
        }
        Xs[kBase + u][rStage] = xe;
        Ws[kBase + u][rStage] = we;
      }
    }
    __syncthreads();
#pragma unroll
    for (int kk = 0; kk < 16; ++kk) {
      const float4 a0 = *(const float4*)(&Xs[kk][ty << 2]);
      const float4 a1 = *(const float4*)(&Xs[kk][64 + (ty << 2)]);
      const float4 b0 = *(const float4*)(&Ws[kk][tx << 2]);
      const float4 b1 = *(const float4*)(&Ws[kk][64 + (tx << 2)]);
      const float av[8] = {a0.x, a0.y, a0.z, a0.w, a1.x, a1.y, a1.z, a1.w};
      const float bw[8] = {b0.x, b0.y, b0.z, b0.w, b1.x, b1.y, b1.z, b1.w};
#pragma unroll
      for (int i = 0; i < 8; ++i)
#pragma unroll
        for (int j = 0; j < 8; ++j) acc[i][j] = fmaf(av[i], bw[j], acc[i][j]);
    }
    __syncthreads();
  }
  if constexpr (!FUSE_MAX) {
#pragma unroll
    for (int h = 0; h < 2; ++h)
#pragma unroll
      for (int i = 0; i < 4; ++i) {
        const int r = r0 + h * 64 + (ty << 2) + i;
        float* yr = Y + (size_t)r * Cout;
#pragma unroll
        for (int g = 0; g < 2; ++g) {
          const int n = n0 + g * 64 + (tx << 2);
          if (n < Cout) {
            float4 o = {acc[h * 4 + i][g * 4 + 0], acc[h * 4 + i][g * 4 + 1],
                        acc[h * 4 + i][g * 4 + 2], acc[h * 4 + i][g * 4 + 3]};
            *(float4*)(yr + n) = o;
          }
        }
      }
  }
  // stats epilogue: per-column partials -> LDS reduce -> binned atomics
#pragma unroll
  for (int g = 0; g < 2; ++g)
#pragma unroll
    for (int j = 0; j < 4; ++j) {
      float s = 0.f, q = 0.f;
#pragma unroll
      for (int rh = 0; rh < 8; ++rh) {
        const float v = acc[rh][g * 4 + j];
        s += v;
        q = fmaf(v, v, q);
      }
      Xs[ty][g * 64 + (tx << 2) + j] = s;
      Ws[ty][g * 64 + (tx << 2) + j] = q;
    }
  __syncthreads();
  if (t < 128) {
    const int n = n0 + t;
    if (n < Cout) {
      float s = 0.f, q = 0.f;
#pragma unroll
      for (int w = 0; w < 16; ++w) { s += Xs[w][t]; q += Ws[w][t]; }
      float* dst = st_out + (blockIdx.x & (NBINS - 1)) * 2 * Cout;
      atomicAdd(dst + n, s);
      atomicAdd(dst + Cout + n, q);
    }
  }
  // maxpool epilogue: ns in {32, 64, 128}
  if constexpr (FUSE_MAX) {
    __syncthreads();  // stats reduce done reading Xs/Ws
    float mxAll = NEG_INF;  // used only for ns==128 path (t<128)
#pragma unroll
    for (int h = 0; h < 2; ++h) {
      // thread's per-col max over its 4 rows in this half
#pragma unroll
      for (int g2 = 0; g2 < 2; ++g2)
#pragma unroll
        for (int j = 0; j < 4; ++j) {
          float mx = acc[h * 4 + 0][g2 * 4 + j];
          mx = fmaxf(mx, acc[h * 4 + 1][g2 * 4 + j]);
          mx = fmaxf(mx, acc[h * 4 + 2][g2 * 4 + j]);
          mx = fmaxf(mx, acc[h * 4 + 3][g2 * 4 + j]);
          Xs[ty][g2 * 64 + (tx << 2) + j] = mx;
        }
      __syncthreads();
      if (t < 128) {
        const int n = n0 + t;
        if (n < Cout) {
          if (ns <= 64) {
            const int tpg = ns >> 2;        // ty's per group
            const int gph = 64 / ns;        // groups per 64-row half
            for (int gq = 0; gq < gph; ++gq) {
              float mx = NEG_INF;
              for (int w = gq * tpg; w < gq * tpg + tpg; ++w) mx = fmaxf(mx, Xs[w][t]);
              const int g = (r0 + h * 64) / ns + gq;
              pooled[(size_t)g * Cout + n] = mx;
            }
          } else {  // ns == 128: single group spans both halves
            float mx = NEG_INF;
            for (int w = 0; w < 16; ++w) mx = fmaxf(mx, Xs[w][t]);
            mxAll = fmaxf(mxAll, mx);
          }
        }
      }
      __syncthreads();
    }
    if (ns > 64 && t < 128) {
      const int n = n0 + t;
      if (n < Cout) pooled[(size_t)(r0 >> 7) * Cout + n] = mxAll;
    }
  }
}

// BN apply on an already-pooled G x C buffer (Rtrue = rows of the raw Y)
__global__ void bn_apply_pooled(const float* __restrict__ P, const float* __restrict__ st,
                                float* __restrict__ o, int G, int C, int Rtrue) {
  const int i = blockIdx.x * 256 + threadIdx.x;
  if (i >= G * C) return;
  const int c = i % C;
  float s = 0.f, q = 0.f;
#pragma unroll
  for (int bn = 0; bn < NBINS; ++bn) {
    s += st[bn * 2 * C + c];
    q += st[bn * 2 * C + C + c];
  }
  const float inv = 1.f / (float)Rtrue;
  const float m  = s * inv;
  const float vr = fmaf(-m, m, q * inv);
  const float sc = rsqrtf(vr + EPS_BN);
  o[i] = fmaxf(0.f, (P[i] - m) * sc);
}

// normalize -> relu -> max over ns rows per group (gripper path, ns=512)
__global__ void bn_apply_relu_maxpool(const float* __restrict__ Y,
                                      const float* __restrict__ st,
                                      float* __restrict__ o, int G, int ns, int C) {
  const int i = blockIdx.x * 256 + threadIdx.x;
  if (i >= G * C) return;
  const int c = i % C;
  const int g = i / C;
  float s = 0.f, q = 0.f;
#pragma unroll
  for (int bn = 0; bn < NBINS; ++bn) {
    s += st[bn * 2 * C + c];
    q += st[bn * 2 * C + C + c];
  }
  const int R = G * ns;
  const float inv = 1.f / (float)R;
  const float m  = s * inv;
  const float vr = fmaf(-m, m, q * inv);
  const float sc = rsqrtf(vr + EPS_BN);
  const float* p = Y + (size_t)g * ns * C + c;
  float mx = NEG_INF;
  for (int k = 0; k < ns; ++k) mx = fmaxf(mx, p[(size_t)k * C]);
  o[i] = fmaxf(0.f, (mx - m) * sc);
}

// =====================================================================
// FPS for SA1 (N=20000 -> 512), R5-EXACT kernel (1415-1417 us measured,
// passed + replay-stable). FINAL: 8 structural experiments (R5-R13)
// bracketed the serial floor; dense 16-wave scan with strided ownership
// and the 2-barrier owner-detect reduce wins. DO NOT MODIFY.
// =====================================================================
#define REPA(X) X(0) X(1) X(2) X(3) X(4) X(5) X(6) X(7) X(8) X(9) X(10) X(11)
#define REPB(X) X(12) X(13) X(14) X(15) X(16) X(17) X(18) X(19)

__global__ __launch_bounds__(1024)
void fps_sa1_kernel(const float* __restrict__ xyz, float* __restrict__ new_xyz) {
  const int b    = blockIdx.x;
  const int tid  = threadIdx.x;
  const int lane = tid & 63;
  const int wave = tid >> 6;  // 0..15
  const float* p = xyz + (size_t)b * 20000 * 3;

  __shared__ float ddL[12 * 1024];  // 48 KB; bank = tid%32 -> free 2-way
  __shared__ float sv[16], sx[16], sy[16], sz[16];
  __shared__ int   si[16];
  __shared__ float bc[3];

#define DECLR(k) float px##k, py##k, pz##k, dd##k;
  REPB(DECLR)
#undef DECLR

#define INITL(k) ddL[(k) * 1024 + tid] = 1e10f;
  REPA(INITL)
#undef INITL
#define INITR(k) {                                                          \
    const int i = tid + (k) * 1024;                                         \
    if (i < 20000) {                                                        \
      px##k = p[i * 3 + 0]; py##k = p[i * 3 + 1]; pz##k = p[i * 3 + 2];     \
      dd##k = 1e10f;                                                        \
    } else {                                                                \
      px##k = 0.f; py##k = 0.f; pz##k = 0.f;                                \
      dd##k = NEG_INF;                                                      \
    } }
  REPB(INITR)
#undef INITR

  float fx = p[0], fy = p[1], fz = p[2];
  if (tid == 0) {
    float* o = new_xyz + (size_t)b * 512 * 3;
    o[0] = fx; o[1] = fy; o[2] = fz;
  }
  __syncthreads();

  for (int s = 1; s < 512; ++s) {
    float bv = NEG_INF;
    int   bi = 0x7fffffff;
    float bx = 0.f, by = 0.f, bz = 0.f;
#define SCANS(k) {                                                          \
    const int i = tid + (k) * 1024;                                         \
    const float qx = p[i * 3 + 0], qy = p[i * 3 + 1], qz = p[i * 3 + 2];    \
    const float dx = qx - fx, dy = qy - fy, dz = qz - fz;                   \
    const float d  = __fadd_rn(__fadd_rn(__fmul_rn(dx, dx), __fmul_rn(dy, dy)), \
                               __fmul_rn(dz, dz));                          \
    const float nd = fminf(ddL[(k) * 1024 + tid], d);                       \
    ddL[(k) * 1024 + tid] = nd;                                             \
    if (nd > bv) { bv = nd; bi = i; bx = qx; by = qy; bz = qz; } }
    REPA(SCANS)
#undef SCANS
#define SCANR(k) {                                                          \
    const float dx = px##k - fx, dy = py##k - fy, dz = pz##k - fz;          \
    const float d  = __fadd_rn(__fadd_rn(__fmul_rn(dx, dx), __fmul_rn(dy, dy)), \
                               __fmul_rn(dz, dz));                          \
    const float nd = fminf(dd##k, d);                                       \
    dd##k = nd;                                                             \
    if (nd > bv) { bv = nd; bi = tid + (k) * 1024;                          \
                   bx = px##k; by = py##k; bz = pz##k; } }
    REPB(SCANR)
#undef SCANR
    float v  = bv;
    int   i0 = bi;
#pragma unroll
    for (int m = 1; m < 64; m <<= 1) {
      const float ov = __shfl_xor(v, m, 64);
      const int   oi = __shfl_xor(i0, m, 64);
      if (ov > v || (ov == v && oi < i0)) { v = ov; i0 = oi; }
    }
    if (i0 == bi) {  // unique owner lane of this wave's winner
      sv[wave] = bv; si[wave] = bi; sx[wave] = bx; sy[wave] = by; sz[wave] = bz;
    }
    __syncthreads();
    if (tid < 64) {
      const float lv = (lane < 16) ? sv[lane] : NEG_INF;
      const int   li = (lane < 16) ? si[lane] : 0x7fffffff;
      float v2 = lv;
      int   i2 = li;
#pragma unroll
      for (int m = 1; m < 16; m <<= 1) {
        const float ov = __shfl_xor(v2, m, 64);
        const int   oi = __shfl_xor(i2, m, 64);
        if (ov > v2 || (ov == v2 && oi < i2)) { v2 = ov; i2 = oi; }
      }
      if (lane < 16 && li == i2) {  // unique global owner
        const float wx = sx[lane], wy = sy[lane], wz = sz[lane];
        bc[0] = wx; bc[1] = wy; bc[2] = wz;
        float* o = new_xyz + ((size_t)b * 512 + s) * 3;
        o[0] = wx; o[1] = wy; o[2] = wz;
      }
    }
    __syncthreads();
    fx = bc[0]; fy = bc[1]; fz = bc[2];
  }
}

// =====================================================================
// FPS small (SA2: 512 -> 128), one block per batch, all state in regs.
// =====================================================================
template <int N, int NP, int THREADS, int NPT>
__global__ __launch_bounds__(THREADS)
void fps2_kernel(const float* __restrict__ xyz, float* __restrict__ new_xyz) {
  constexpr int NW = THREADS / 64;
  const int b    = blockIdx.x;
  const int tid  = threadIdx.x;
  const int lane = tid & 63;
  const int wave = tid >> 6;
  const float* p = xyz + (size_t)b * N * 3;
  float px[NPT], py[NPT], pz[NPT], dd[NPT];
#pragma unroll
  for (int j = 0; j < NPT; ++j) {
    const int i = tid + j * THREADS;
    if (i < N) {
      px[j] = p[i * 3 + 0];
      py[j] = p[i * 3 + 1];
      pz[j] = p[i * 3 + 2];
      dd[j] = 1e10f;
    } else {
      px[j] = 0.f; py[j] = 0.f; pz[j] = 0.f;
      dd[j] = NEG_INF;
    }
  }
  __shared__ float sv[NW], sx[NW], sy[NW], sz[NW];
  __shared__ int   si[NW];
  __shared__ float bc[3];
  float fx = p[0], fy = p[1], fz = p[2];
  if (tid == 0) {
    float* o = new_xyz + (size_t)b * NP * 3;
    o[0] = fx; o[1] = fy; o[2] = fz;
  }
  for (int s = 1; s < NP; ++s) {
    float bv = NEG_INF;
    int   bi = 0x7fffffff;
    float bx = 0.f, by = 0.f, bz = 0.f;
#pragma unroll
    for (int j = 0; j < NPT; ++j) {
      const float dx = px[j] - fx;
      const float dy = py[j] - fy;
      const float dz = pz[j] - fz;
      const float d  = __fadd_rn(__fadd_rn(__fmul_rn(dx, dx), __fmul_rn(dy, dy)),
                                 __fmul_rn(dz, dz));
      const float nd = fminf(dd[j], d);
      dd[j] = nd;
      if (nd > bv) { bv = nd; bi = tid + j * THREADS; bx = px[j]; by = py[j]; bz = pz[j]; }
    }
    float v = bv;
    int   i0 = bi;
#pragma unroll
    for (int m = 1; m < 64; m <<= 1) {
      const float ov = __shfl_xor(v, m, 64);
      const int   oi = __shfl_xor(i0, m, 64);
      if (ov > v || (ov == v && oi < i0)) { v = ov; i0 = oi; }
    }
    if (i0 == bi) {
      sv[wave] = bv; si[wave] = bi; sx[wave] = bx; sy[wave] = by; sz[wave] = bz;
    }
    __syncthreads();
    if (tid < 64) {
      const float lv = (lane < NW) ? sv[lane] : NEG_INF;
      const int   li = (lane < NW) ? si[lane] : 0x7fffffff;
      float v2 = lv;
      int   i2 = li;
#pragma unroll
      for (int m = 1; m < NW; m <<= 1) {
        const float ov = __shfl_xor(v2, m, 64);
        const int   oi = __shfl_xor(i2, m, 64);
        if (ov > v2 || (ov == v2 && oi < i2)) { v2 = ov; i2 = oi; }
      }
      if (lane < NW && li == i2) {
        const float wx = sx[lane], wy = sy[lane], wz = sz[lane];
        bc[0] = wx; bc[1] = wy; bc[2] = wz;
        float* o = new_xyz + ((size_t)b * NP + s) * 3;
        o[0] = wx; o[1] = wy; o[2] = wz;
      }
    }
    __syncthreads();
    fx = bc[0]; fy = bc[1]; fz = bc[2];
  }
}

// =====================================================================
// Ball query: ONE WAVE PER CENTER, ballot + prefix-popcount (R11,
// validated). Emits the first NS qualifying indices in ascending order.
// =====================================================================
template <int N, int NS>
__global__ __launch_bounds__(256)
void ballquery_wave_kernel(const float* __restrict__ centers,
                           const float* __restrict__ pts,
                           int* __restrict__ idx, int BS, int S, float r2) {
  const int w    = (blockIdx.x * 256 + threadIdx.x) >> 6;  // global wave id
  const int lane = threadIdx.x & 63;
  if (w >= BS) return;
  const int b = w / S;
  const float cx = centers[w * 3 + 0];
  const float cy = centers[w * 3 + 1];
  const float cz = centers[w * 3 + 2];
  const float* p = pts + (size_t)b * N * 3;
  int* o = idx + (size_t)w * NS;
  int total = 0;
  int first = -1;
  for (int i0 = 0; i0 < N && total < NS; i0 += 64) {
    const int i = i0 + lane;
    bool pred = false;
    if (i < N) {
      const float dx = cx - p[i * 3 + 0];
      const float dy = cy - p[i * 3 + 1];
      const float dz = cz - p[i * 3 + 2];
      const float d2 = __fadd_rn(__fadd_rn(__fmul_rn(dx, dx), __fmul_rn(dy, dy)),
                                 __fmul_rn(dz, dz));
      pred = (d2 < r2);
    }
    const unsigned long long mask = __ballot(pred);
    if (mask) {
      const unsigned long long below = (lane == 0) ? 0ull : (mask << (64 - lane));
      const int before = __popcll(below);
      if (pred && (total + before) < NS) o[total + before] = i;
      if (first < 0) first = i0 + (__ffsll((long long)mask) - 1);  // wave-uniform
      total += __popcll(mask);
    }
  }
  if (lane >= total && lane < NS) o[lane] = first;
}

// =====================================================================
// Grouping / concat kernels
// =====================================================================
__global__ void group1_kernel(const float* __restrict__ xyz, const float* __restrict__ ctr,
                              const int* __restrict__ idx, float* __restrict__ X1) {
  const int t = blockIdx.x * 256 + threadIdx.x;
  if (t >= 8 * 512 * 32) return;
  const int g = t >> 5;
  const int b = g >> 9;
  const int i = idx[t];
  const float* p = xyz + ((size_t)b * 20000 + i) * 3;
  const float* c = ctr + (size_t)g * 3;
  X1[t * 3 + 0] = (p[0] - c[0]) / 0.2f;
  X1[t * 3 + 1] = (p[1] - c[1]) / 0.2f;
  X1[t * 3 + 2] = (p[2] - c[2]) / 0.2f;
}

__global__ void group2_kernel(const float* __restrict__ xyz1,
                              const float* __restrict__ xyz2,
                              const float* __restrict__ f1,
                              const int* __restrict__ idx2,
                              float* __restrict__ X2) {
  const int t = blockIdx.x * 256 + threadIdx.x;
  if (t >= 65536 * 131) return;
  const int r = t / 131;
  const int c = t - r * 131;
  const int g = r >> 6;
  const int b = g >> 7;
  const int i = idx2[r];
  float v;
  if (c < 3) {
    v = (xyz1[((size_t)b * 512 + i) * 3 + c] - xyz2[(size_t)g * 3 + c]) / 0.4f;
  } else {
    v = f1[((size_t)b * 512 + i) * 128 + (c - 3)];
  }
  X2[t] = v;
}

__global__ void build_x3_kernel(const float* __restrict__ xyz2, const float* __restrict__ f2,
                                float* __restrict__ X3) {
  const int t = blockIdx.x * 256 + threadIdx.x;
  if (t >= 1024 * 259) return;
  const int r = t / 259;
  const int c = t - r * 259;
  X3[t] = (c < 3) ? xyz2[r * 3 + c] : f2[(size_t)r * 256 + (c - 3)];
}

// =====================================================================
// Fused head — float4 weight + LDS reads (R11, validated)
// =====================================================================
__global__ __launch_bounds__(512) void head_kernel(
    const float* __restrict__ gfeat, const float* __restrict__ objf,
    const float* __restrict__ w0, const float* __restrict__ b0,
    const float* __restrict__ w1, const float* __restrict__ b1,
    const float* __restrict__ w2, const float* __restrict__ b2,
    float* __restrict__ out) {
  __shared__ __align__(16) float comb[8 * 1152];
  __shared__ __align__(16) float h1[8 * 512];
  __shared__ __align__(16) float h2[8 * 256];
  const int tid = threadIdx.x;
  for (int i = tid; i < 8 * 1152; i += 512) {
    const int b = i / 1152, c = i - b * 1152;
    comb[i] = (c < 128) ? gfeat[b * 128 + c] : objf[b * 1024 + (c - 128)];
  }
  __syncthreads();
  for (int c = tid; c < 1152; c += 512) {
    float s = 0.f;
#pragma unroll
    for (int b = 0; b < 8; ++b) s += comb[b * 1152 + c];
    const float m = s * 0.125f;
    float v = 0.f;
#pragma unroll
    for (int b = 0; b < 8; ++b) { const float d = comb[b * 1152 + c] - m; v = fmaf(d, d, v); }
    const float sc = rsqrtf(v * 0.125f + EPS_BN);
#pragma unroll
    for (int b = 0; b < 8; ++b) comb[b * 1152 + c] = (comb[b * 1152 + c] - m) * sc;
  }
  __syncthreads();
  {  // layer 0: 1152 -> 512, float4 over k
    float a[8];
#pragma unroll
    for (int b = 0; b < 8; ++b) a[b] = b0[tid];
    const float* wr = w0 + (size_t)tid * 1152;
    for (int ci = 0; ci < 1152; ci += 4) {
      const float4 wv = *(const float4*)(wr + ci);
#pragma unroll
      for (int b = 0; b < 8; ++b) {
        const float4 xv = *(const float4*)(&comb[b * 1152 + ci]);
        a[b] = fmaf(xv.x, wv.x, a[b]);
        a[b] = fmaf(xv.y, wv.y, a[b]);
        a[b] = fmaf(xv.z, wv.z, a[b]);
        a[b] = fmaf(xv.w, wv.w, a[b]);
      }
    }
    float s = 0.f;
#pragma unroll
    for (int b = 0; b < 8; ++b) s += a[b];
    const float m = s * 0.125f;
    float v = 0.f;
#pragma unroll
    for (int b = 0; b < 8; ++b) { const float d = a[b] - m; v = fmaf(d, d, v); }
    const float sc = rsqrtf(v * 0.125f + EPS_BN);
#pragma unroll
    for (int b = 0; b < 8; ++b) h1[b * 512 + tid] = fmaxf(0.f, (a[b] - m) * sc);
  }
  __syncthreads();
  if (tid < 256) {  // layer 1: 512 -> 256, float4 over k
    float a[8];
#pragma unroll
    for (int b = 0; b < 8; ++b) a[b] = b1[tid];
    const float* wr = w1 + (size_t)tid * 512;
    for (int ci = 0; ci < 512; ci += 4) {
      const float4 wv = *(const float4*)(wr + ci);
#pragma unroll
      for (int b = 0; b < 8; ++b) {
        const float4 xv = *(const float4*)(&h1[b * 512 + ci]);
        a[b] = fmaf(xv.x, wv.x, a[b]);
        a[b] = fmaf(xv.y, wv.y, a[b]);
        a[b] = fmaf(xv.z, wv.z, a[b]);
        a[b] = fmaf(xv.w, wv.w, a[b]);
      }
    }
    float s = 0.f;
#pragma unroll
    for (int b = 0; b < 8; ++b) s += a[b];
    const float m = s * 0.125f;
    float v = 0.f;
#pragma unroll
    for (int b = 0; b < 8; ++b) { const float d = a[b] - m; v = fmaf(d, d, v); }
    const float sc = rsqrtf(v * 0.125f + EPS_BN);
#pragma unroll
    for (int b = 0; b < 8; ++b) h2[b * 256 + tid] = fmaxf(0.f, (a[b] - m) * sc);
  }
  __syncthreads();
  if (tid < 8) {  // layer 2: 256 -> 1, relu
    float s = b2[0];
    for (int ci = 0; ci < 256; ++ci) s = fmaf(h2[tid * 256 + ci], w2[ci], s);
    out[tid] = fmaxf(0.f, s);
  }
}

// =====================================================================
// Host orchestration
// =====================================================================
extern "C" void kernel_launch(void* const* d_in, const int* in_sizes, int n_in,
                              void* d_out, int out_size, void* d_ws, size_t ws_size,
                              hipStream_t stream) {
  (void)in_sizes; (void)n_in; (void)out_size; (void)ws_size;
  const float* obj  = (const float*)d_in[0];
  const float* grip = (const float*)d_in[1];
  const float* s1w0 = (const float*)d_in[2];
  const float* s1w1 = (const float*)d_in[3];
  const float* s1w2 = (const float*)d_in[4];
  const float* s2w0 = (const float*)d_in[5];
  const float* s2w1 = (const float*)d_in[6];
  const float* s2w2 = (const float*)d_in[7];
  const float* s3w0 = (const float*)d_in[8];
  const float* s3w1 = (const float*)d_in[9];
  const float* s3w2 = (const float*)d_in[10];
  const float* gw0  = (const float*)d_in[11];
  const float* gw1  = (const float*)d_in[12];
  const float* gw2  = (const float*)d_in[13];
  const float* hw0  = (const float*)d_in[14];
  const float* hb0  = (const float*)d_in[15];
  const float* hw1  = (const float*)d_in[16];
  const float* hb1  = (const float*)d_in[17];
  const float* hw2  = (const float*)d_in[18];
  const float* hb2  = (const float*)d_in[19];
  float* out = (float*)d_out;

  // ---- workspace layout (float offsets); total 26,658,304 floats ----
  float* wsf   = (float*)d_ws;
  float* stats = wsf;
  float* xyz1  = wsf + 23040;
  float* xyz2  = wsf + 35328;
  float* gfeat = wsf + 38400;
  float* objf  = wsf + 39424;
  float* f1    = wsf + 47616;
  float* f2    = wsf + 571904;
  float* x3    = wsf + 834048;
  int*   idx1  = (int*)(wsf + 1099264);
  int*   idx2  = (int*)(wsf + 1230336);
  float* bufP  = wsf + 1295872;
  float* bufQ  = wsf + 18073088;

  static const int st_off[12] = {0, 512, 1536, 2560, 3072, 3584,
                                 4608, 5632, 6656, 8704, 10752, 14848};
  auto st = [&](int li) { return stats + st_off[li]; };

  hipMemsetAsync(stats, 0, 23040 * sizeof(float), stream);

  auto gemm0 = [&](const float* X, const float* Wm, float* Y, int R, int Cin, int Cout,
                   int lo) {
    dim3 g((R + 127) / 128, (Cout + 127) / 128);
    gemm_xwt<false, false><<<g, 256, 0, stream>>>(X, Wm, Y, R, Cin, Cout, nullptr, 0,
                                                  st(lo), nullptr, 0);
  };
  auto gemmf = [&](const float* X, const float* Wm, float* Y, int R, int Cin, int Cout,
                   int li, int lo) {
    dim3 g((R + 127) / 128, (Cout + 127) / 128);
    gemm_xwt<true, false><<<g, 256, 0, stream>>>(X, Wm, Y, R, Cin, Cout, st(li), R,
                                                 st(lo), nullptr, 0);
  };
  auto gemmfM = [&](const float* X, const float* Wm, float* pooled, int R, int Cin,
                    int Cout, int li, int lo, int ns) {
    dim3 g((R + 127) / 128, (Cout + 127) / 128);
    gemm_xwt<true, true><<<g, 256, 0, stream>>>(X, Wm, nullptr, R, Cin, Cout, st(li), R,
                                                st(lo), pooled, ns);
  };
  auto applymax_k = [&](const float* Y, int li, int G, int ns, int C, float* o) {
    const int n = G * C;
    bn_apply_relu_maxpool<<<(n + 255) / 256, 256, 0, stream>>>(Y, st(li), o, G, ns, C);
  };
  auto applypool_k = [&](const float* P, int li, int G, int C, int Rtrue, float* o) {
    const int n = G * C;
    bn_apply_pooled<<<(n + 255) / 256, 256, 0, stream>>>(P, st(li), o, G, C, Rtrue);
  };

  // ---- SA1 FPS (R5-exact dense-scan kernel) ----
  fps_sa1_kernel<<<8, 1024, 0, stream>>>(obj, xyz1);

  // ---- gripper encoder: [8,512,3] -> 64 -> 128 -> 128 -> maxpool (ns=512 path) ----
  float* gY1 = bufP;
  float* gY2 = bufP + 262144;
  float* gY3 = bufP + 786432;
  gemm0(grip, gw0, gY1, 4096, 3, 64, 0);
  gemmf(gY1, gw1, gY2, 4096, 64, 128, 0, 1);
  gemmf(gY2, gw2, gY3, 4096, 128, 128, 1, 2);
  applymax_k(gY3, 2, 8, 512, 128, gfeat);

  // ---- SA1: ball r=0.2 ns=32 (wave-per-center), MLP 3->64->64->128 ----
  ballquery_wave_kernel<20000, 32><<<1024, 256, 0, stream>>>(xyz1, obj, idx1, 4096, 512, 0.04f);
  float* X1 = bufQ;
  group1_kernel<<<512, 256, 0, stream>>>(obj, xyz1, idx1, X1);
  gemm0(X1, s1w0, bufP, 131072, 3, 64, 3);
  gemmf(bufP, s1w1, bufQ, 131072, 64, 64, 3, 4);
  gemmfM(bufQ, s1w2, bufP, 131072, 64, 128, 4, 5, 32);   // pooled: 4096x128
  applypool_k(bufP, 5, 4096, 128, 131072, f1);

  // ---- SA2: FPS 512->128, ball r=0.4 ns=64, MLP 131->128->128->256 ----
  fps2_kernel<512, 128, 256, 2><<<8, 256, 0, stream>>>(xyz1, xyz2);
  ballquery_wave_kernel<512, 64><<<256, 256, 0, stream>>>(xyz2, xyz1, idx2, 1024, 128, 0.16f);
  float* X2 = bufQ;
  group2_kernel<<<(65536 * 131 + 255) / 256, 256, 0, stream>>>(xyz1, xyz2, f1, idx2, X2);
  gemm0(X2, s2w0, bufP, 65536, 131, 128, 6);
  gemmf(bufP, s2w1, bufQ, 65536, 128, 128, 6, 7);
  gemmfM(bufQ, s2w2, bufP, 65536, 128, 256, 7, 8, 64);   // pooled: 1024x256
  applypool_k(bufP, 8, 1024, 256, 65536, f2);

  // ---- SA3 (group_all): concat[xyz2,f2] -> 256 -> 512 -> 1024 -> maxpool ----
  build_x3_kernel<<<(1024 * 259 + 255) / 256, 256, 0, stream>>>(xyz2, f2, x3);
  float* Y3a = bufQ;
  float* Y3b = bufQ + 262144;
  float* Y3p = bufQ + 786432;
  gemm0(x3, s3w0, Y3a, 1024, 259, 256, 9);
  gemmf(Y3a, s3w1, Y3b, 1024, 256, 512, 9, 10);
  gemmfM(Y3b, s3w2, Y3p, 1024, 512, 1024, 10, 11, 128);  // pooled: 8x1024
  applypool_k(Y3p, 11, 8, 1024, 1024, objf);

  // ---- head ----
  head_kernel<<<1, 512, 0, stream>>>(gfeat, objf, hw0, hb0, hw1, hb1, hw2, hb2, out);
}